// Round 1
// 8931.765 us; speedup vs baseline: 1.0095x; 1.0095x over previous
//
#include <hip/hip_runtime.h>
#include <hip/hip_bf16.h>

// SentenceClassifier: LSTM(B=64,T=512,E=512,H=1024) -> h_T @ outW + outb -> softmax/CE
// Persistent-kernel design: 128 blocks x 256 thr, one block per 8 hidden units
// (32 gate cols = 2 MFMA col-tiles, W slice 96KB in LDS). Internal t-loop with
// CONTENTION-FREE grid barrier: per-block arrival slots (release store, no RMW)
// + parallel poll (thread j of each block spins on slot j). Replaces the single
// atomic counter whose 128 serialized agent-scope RMWs (~140ns each) accounted
// for ~17us/step. c-state in registers; h broadcast via global double buffer.
// x-part MFMAs for t+1 computed between barrier-arrive and spin.

#define Bb 64
#define Tt 512
#define Ee 512
#define Hh 1024
#define Cc 32
#define G4 4096
#define NKS 48     // (E+H)/32
#define NBLK 128
#define HIDB 8     // hid units per block

typedef __attribute__((ext_vector_type(8))) short short8;
typedef __attribute__((ext_vector_type(4))) float f32x4;

__device__ __forceinline__ unsigned short f2bf(float f) {
  __hip_bfloat16 h = __float2bfloat16(f);
  union { __hip_bfloat16 h; unsigned short u; } cv; cv.h = h; return cv.u;
}
static __device__ __forceinline__ float fsig(float x) { return 1.0f / (1.0f + __expf(-x)); }
static __device__ __forceinline__ float ftanhf(float x) {
  float e = __expf(-2.0f * fabsf(x));
  float t = (1.0f - e) / (1.0f + e);
  return copysignf(t, x);
}

// ---- x [B,T,E] f32 -> xT [T,B,E] bf16 (contiguous 64KB window per step) ----
__global__ __launch_bounds__(256) void transpose_x_kernel(const float* __restrict__ x,
                                                          unsigned short* __restrict__ xT) {
  const int bid = blockIdx.x;          // row*Tt + t
  const int row = bid >> 9, t = bid & (Tt - 1);
  const int e = threadIdx.x * 2;
  const float* src = x + ((size_t)row * Tt + t) * Ee + e;
  float2 v = *(const float2*)src;
  ushort2 o; o.x = f2bf(v.x); o.y = f2bf(v.y);
  *(ushort2*)(xT + ((size_t)t * Bb + row) * Ee + e) = o;
}

// ---- W [1536,4096] f32 -> per-block B-frag-packed bf16 --------------------
// Block bc owns hid in [bc*8, bc*8+8). Col-tile tau in {0,1}: lane col c=l&15 maps
// to gate g = 2*tau + (c>>3), hid = bc*8 + (c&7). Lane l holds
// B[k = ks*32 + (l>>4)*8 + i][col = g*1024 + hid], i=0..7 (one short8 = 16B).
__global__ __launch_bounds__(64) void pack_w_kernel(const float* __restrict__ W,
                                                    unsigned short* __restrict__ Wpk) {
  const int fid = blockIdx.x;          // blk*96 + tau*48 + ks
  const int l = threadIdx.x;
  const int blk = fid / 96, rem = fid % 96;
  const int tau = rem / 48, ks = rem % 48;
  const int c = l & 15;
  const int col = (2 * tau + (c >> 3)) * Hh + blk * HIDB + (c & 7);
  const int k0 = ks * 32 + (l >> 4) * 8;
  short8 v;
#pragma unroll
  for (int i = 0; i < 8; i++) v[i] = (short)f2bf(W[(size_t)(k0 + i) * G4 + col]);
  *(short8*)(Wpk + ((size_t)fid * 64 + l) * 8) = v;
}

// ---- zero h0 + barrier state ---------------------------------------------
__global__ __launch_bounds__(256) void init_state_kernel(unsigned short* __restrict__ h0,
                                                         int* __restrict__ bar) {
  int i = blockIdx.x * 256 + threadIdx.x;   // grid covers Bb*Hh
  h0[i] = 0;
  if (i < NBLK) bar[i] = 0;                 // per-block arrival slots
}

// ---- persistent LSTM kernel ----------------------------------------------
__global__ __launch_bounds__(256) void lstm_persist(
    const unsigned short* __restrict__ xT, const unsigned short* __restrict__ Wpk,
    const float* __restrict__ bias,
    unsigned short* __restrict__ hbuf0, unsigned short* __restrict__ hbuf1,
    float* __restrict__ h_f32, int* __restrict__ bar) {
  __shared__ short8 Wl[2 * NKS * 64];       // 96 KiB
  const int bc = blockIdx.x;
  const int tid = threadIdx.x;

  { // one-time: W slice -> LDS (linear 96KB copy)
    const short8* src = (const short8*)Wpk + (size_t)bc * (2 * NKS * 64);
    for (int i = tid; i < 2 * NKS * 64; i += 256) Wl[i] = src[i];
  }

  const int wv = tid >> 6, ln = tid & 63;
  const int c = ln & 15, kg = ln >> 4;
  const int arow = wv * 16 + c;        // A-frag row = batch index
  const int rbase = wv * 16 + kg * 4;  // D rows (m89 layout: row=(l>>4)*4+r, col=l&15)
  const int hid = bc * HIDB + (c & 7);
  const bool lo = (c < 8);
  const float bi = bias[hid], bj = bias[Hh + hid];
  const float bff = bias[2 * Hh + hid], bo = bias[3 * Hh + hid];
  float cstate[4] = {0.f, 0.f, 0.f, 0.f};
  int* arr = bar;                      // NBLK arrival slots (no shared counter)

  __syncthreads();                      // W in LDS ready

  const short8* W0 = Wl;                // tile0 (gates i,j)
  const short8* W1 = Wl + NKS * 64;     // tile1 (gates f,o)

  f32x4 xa0, xa1;
  // x-part for t=0
  {
    const unsigned short* xr = xT + ((size_t)0 * Bb + arow) * Ee + kg * 8;
    f32x4 a0 = {0.f,0.f,0.f,0.f}, a1 = {0.f,0.f,0.f,0.f};
#pragma unroll 8
    for (int kk = 0; kk < 16; kk++) {
      short8 a = *(const short8*)(xr + kk * 32);
      a0 = __builtin_amdgcn_mfma_f32_16x16x32_bf16(a, W0[kk * 64 + ln], a0, 0, 0, 0);
      a1 = __builtin_amdgcn_mfma_f32_16x16x32_bf16(a, W1[kk * 64 + ln], a1, 0, 0, 0);
    }
    xa0 = a0; xa1 = a1;
  }

  for (int t = 0; t < Tt; t++) {
    const unsigned short* hin = (t & 1) ? hbuf1 : hbuf0;
    unsigned short* hout = (t & 1) ? hbuf0 : hbuf1;
    f32x4 a0 = xa0, a1 = xa1;
    const unsigned short* hr = hin + arow * Hh + kg * 8;
#pragma unroll 8
    for (int kk = 0; kk < 32; kk++) {
      short8 a = *(const short8*)(hr + kk * 32);
      a0 = __builtin_amdgcn_mfma_f32_16x16x32_bf16(a, W0[(16 + kk) * 64 + ln], a0, 0, 0, 0);
      a1 = __builtin_amdgcn_mfma_f32_16x16x32_bf16(a, W1[(16 + kk) * 64 + ln], a1, 0, 0, 0);
    }
    // cell update: tile0 lane c<8 holds i (c>=8: j), tile1 holds f (o). One
    // shfl_xor(8) gives each lane all 4 gates; lane pair (c, c^8) redundant.
    float hnew[4];
#pragma unroll
    for (int r = 0; r < 4; r++) {
      const float p0 = a0[r], p1 = a1[r];
      const float s0 = __shfl_xor(p0, 8), s1 = __shfl_xor(p1, 8);
      const float gi = (lo ? p0 : s0) + bi;
      const float gj = (lo ? s0 : p0) + bj;
      const float gf = (lo ? p1 : s1) + bff;
      const float go = (lo ? s1 : p1) + bo;
      const float cn = cstate[r] * fsig(gf + 1.0f) + fsig(gi) * ftanhf(gj);
      cstate[r] = cn;
      hnew[r] = ftanhf(cn) * fsig(go);
    }
    if (t < Tt - 1) {
      if (lo) {
#pragma unroll
        for (int r = 0; r < 4; r++) hout[(rbase + r) * Hh + hid] = f2bf(hnew[r]);
      }
      __syncthreads();                  // block's h writes drained (vmcnt(0) at barrier)
      if (tid == 0) {
        __threadfence();                // release: flush h to device scope
        __hip_atomic_store(&arr[bc], t + 1, __ATOMIC_RELEASE, __HIP_MEMORY_SCOPE_AGENT);
      }
      // hide barrier latency: x-part MFMAs for t+1 (h-independent)
      {
        const unsigned short* xr = xT + ((size_t)(t + 1) * Bb + arow) * Ee + kg * 8;
        f32x4 b0 = {0.f,0.f,0.f,0.f}, b1 = {0.f,0.f,0.f,0.f};
#pragma unroll 8
        for (int kk = 0; kk < 16; kk++) {
          short8 a = *(const short8*)(xr + kk * 32);
          b0 = __builtin_amdgcn_mfma_f32_16x16x32_bf16(a, W0[kk * 64 + ln], b0, 0, 0, 0);
          b1 = __builtin_amdgcn_mfma_f32_16x16x32_bf16(a, W1[kk * 64 + ln], b1, 0, 0, 0);
        }
        xa0 = b0; xa1 = b1;
      }
      // parallel poll: thread j watches block j's slot (coalesced 512B load per
      // iteration, no RMW serialization)
      if (tid < NBLK) {
        while (__hip_atomic_load(&arr[tid], __ATOMIC_RELAXED, __HIP_MEMORY_SCOPE_AGENT) < t + 1)
          __builtin_amdgcn_s_sleep(1);
        __threadfence();                // acquire: invalidate stale h in L1/L2
      }
      __syncthreads();
    } else {
      if (lo) {
#pragma unroll
        for (int r = 0; r < 4; r++) h_f32[(rbase + r) * Hh + hid] = hnew[r];
      }
    }
  }
}

// ---- classifier: pred = h @ outW + outb, softmax, per-row CE --------------
__global__ __launch_bounds__(256) void classifier_kernel(
    const float* __restrict__ h, const float* __restrict__ outW,
    const float* __restrict__ outb, const float* __restrict__ y,
    float* __restrict__ out, float* __restrict__ losses) {
  __shared__ float red[256];
  const int brow = blockIdx.x;
  const int tid = threadIdx.x;
  const int cc = tid & 31;
  const int part = tid >> 5;
  const float* hr = h + brow * Hh;
  float p = 0.f;
  for (int k = part * 128; k < part * 128 + 128; k++)
    p += hr[k] * outW[k * Cc + cc];
  red[tid] = p;
  __syncthreads();
  if (part < 4) red[tid] += red[tid + 128];
  __syncthreads();
  if (part < 2) red[tid] += red[tid + 64];
  __syncthreads();
  if (part < 1) red[tid] += red[tid + 32];
  __syncthreads();
  if (tid < 32) {
    const float logit = red[tid] + outb[tid];
    float m = logit;
    for (int off = 16; off >= 1; off >>= 1) m = fmaxf(m, __shfl_xor(m, off));
    const float e = __expf(logit - m);
    float s = e;
    for (int off = 16; off >= 1; off >>= 1) s += __shfl_xor(s, off);
    out[brow * Cc + tid] = logit;
    out[Bb * Cc + brow * Cc + tid] = e / s;
    const float logp = (logit - m) - __logf(s);
    float contrib = y[brow * Cc + tid] * logp;
    for (int off = 16; off >= 1; off >>= 1) contrib += __shfl_xor(contrib, off);
    if (tid == 0) losses[brow] = -contrib;
  }
}

__global__ __launch_bounds__(64) void finalize_kernel(const float* __restrict__ losses,
                                                      float* __restrict__ out) {
  float v = losses[threadIdx.x];
  for (int off = 32; off >= 1; off >>= 1) v += __shfl_down(v, off);
  if (threadIdx.x == 0) out[2 * Bb * Cc] = v * (1.0f / Bb);
}

extern "C" void kernel_launch(void* const* d_in, const int* in_sizes, int n_in,
                              void* d_out, int out_size, void* d_ws, size_t ws_size,
                              hipStream_t stream) {
  const float* x    = (const float*)d_in[0];
  const float* y    = (const float*)d_in[1];
  // d_in[2] = seqlen (unused)
  const float* W    = (const float*)d_in[3];
  const float* bias = (const float*)d_in[4];
  const float* outW = (const float*)d_in[5];
  const float* outb = (const float*)d_in[6];
  float* out = (float*)d_out;

  char* wsp = (char*)d_ws;
  size_t off = 0;
  auto walloc = [&](size_t bytes) -> void* {
    void* p = wsp + off;
    off += (bytes + 255) & ~(size_t)255;
    return p;
  };
  unsigned short* xT   = (unsigned short*)walloc((size_t)Bb * Tt * Ee * 2);       // 32 MiB
  unsigned short* Wpk  = (unsigned short*)walloc((size_t)NBLK * 2 * NKS * 64 * 16); // 12 MiB
  unsigned short* hbf0 = (unsigned short*)walloc((size_t)Bb * Hh * 2);
  unsigned short* hbf1 = (unsigned short*)walloc((size_t)Bb * Hh * 2);
  float* hf     = (float*)walloc((size_t)Bb * Hh * 4);
  float* losses = (float*)walloc(256);
  int* bar      = (int*)walloc(1024);
  (void)ws_size; (void)in_sizes; (void)n_in; (void)out_size;

  transpose_x_kernel<<<Bb * Tt, 256, 0, stream>>>(x, xT);
  pack_w_kernel<<<NBLK * 2 * NKS, 64, 0, stream>>>(W, Wpk);
  init_state_kernel<<<(Bb * Hh) / 256, 256, 0, stream>>>(hbf0, bar);

  lstm_persist<<<NBLK, 256, 0, stream>>>(xT, Wpk, bias, hbf0, hbf1, hf, bar);

  classifier_kernel<<<Bb, 256, 0, stream>>>(hf, outW, outb, y, out, losses);
  finalize_kernel<<<1, 64, 0, stream>>>(losses, out);
}

// Round 2
// 5851.744 us; speedup vs baseline: 1.5409x; 1.5263x over previous
//
#include <hip/hip_runtime.h>
#include <hip/hip_bf16.h>

// SentenceClassifier: LSTM(B=64,T=512,E=512,H=1024) -> h_T @ outW + outb -> softmax/CE
// Persistent-kernel design: 128 blocks x 256 thr, one block per 8 hidden units
// (32 gate cols = 2 MFMA col-tiles, W slice 96KB in LDS). Internal t-loop with
// per-block arrival slots + parallel poll. FENCE-FREE t-loop: h is exchanged via
// agent-scope coherent (sc0/sc1) atomic loads/stores that bypass L1/L2 and hit
// the LLC directly -- no __threadfence (buffer_wbl2+buffer_inv) anywhere in the
// loop. L2 stays warm for the xT windows (shared by 16 blocks/XCD). h loads are
// register-batched (64x8B issued up front) to collapse 4 serialized LLC-latency
// groups into 1. x-part MFMAs for t+1 computed between arrive and spin.

#define Bb 64
#define Tt 512
#define Ee 512
#define Hh 1024
#define Cc 32
#define G4 4096
#define NKS 48     // (E+H)/32
#define NBLK 128
#define HIDB 8     // hid units per block

typedef __attribute__((ext_vector_type(8))) short short8;
typedef __attribute__((ext_vector_type(4))) float f32x4;

__device__ __forceinline__ unsigned short f2bf(float f) {
  __hip_bfloat16 h = __float2bfloat16(f);
  union { __hip_bfloat16 h; unsigned short u; } cv; cv.h = h; return cv.u;
}
static __device__ __forceinline__ float fsig(float x) { return 1.0f / (1.0f + __expf(-x)); }
static __device__ __forceinline__ float ftanhf(float x) {
  float e = __expf(-2.0f * fabsf(x));
  float t = (1.0f - e) / (1.0f + e);
  return copysignf(t, x);
}

// ---- x [B,T,E] f32 -> xT [T,B,E] bf16 (contiguous 64KB window per step) ----
__global__ __launch_bounds__(256) void transpose_x_kernel(const float* __restrict__ x,
                                                          unsigned short* __restrict__ xT) {
  const int bid = blockIdx.x;          // row*Tt + t
  const int row = bid >> 9, t = bid & (Tt - 1);
  const int e = threadIdx.x * 2;
  const float* src = x + ((size_t)row * Tt + t) * Ee + e;
  float2 v = *(const float2*)src;
  ushort2 o; o.x = f2bf(v.x); o.y = f2bf(v.y);
  *(ushort2*)(xT + ((size_t)t * Bb + row) * Ee + e) = o;
}

// ---- W [1536,4096] f32 -> per-block B-frag-packed bf16 --------------------
__global__ __launch_bounds__(64) void pack_w_kernel(const float* __restrict__ W,
                                                    unsigned short* __restrict__ Wpk) {
  const int fid = blockIdx.x;          // blk*96 + tau*48 + ks
  const int l = threadIdx.x;
  const int blk = fid / 96, rem = fid % 96;
  const int tau = rem / 48, ks = rem % 48;
  const int c = l & 15;
  const int col = (2 * tau + (c >> 3)) * Hh + blk * HIDB + (c & 7);
  const int k0 = ks * 32 + (l >> 4) * 8;
  short8 v;
#pragma unroll
  for (int i = 0; i < 8; i++) v[i] = (short)f2bf(W[(size_t)(k0 + i) * G4 + col]);
  *(short8*)(Wpk + ((size_t)fid * 64 + l) * 8) = v;
}

// ---- zero h0 + barrier state ---------------------------------------------
__global__ __launch_bounds__(256) void init_state_kernel(unsigned short* __restrict__ h0,
                                                         int* __restrict__ bar) {
  int i = blockIdx.x * 256 + threadIdx.x;   // grid covers Bb*Hh
  h0[i] = 0;
  if (i < NBLK) bar[i] = 0;                 // per-block arrival slots
}

// ---- persistent LSTM kernel ----------------------------------------------
__global__ __launch_bounds__(256, 1) void lstm_persist(
    const unsigned short* __restrict__ xT, const unsigned short* __restrict__ Wpk,
    const float* __restrict__ bias,
    unsigned short* __restrict__ hbuf0, unsigned short* __restrict__ hbuf1,
    float* __restrict__ h_f32, int* __restrict__ bar) {
  __shared__ short8 Wl[2 * NKS * 64];       // 96 KiB
  const int bc = blockIdx.x;
  const int tid = threadIdx.x;

  { // one-time: W slice -> LDS (linear 96KB copy)
    const short8* src = (const short8*)Wpk + (size_t)bc * (2 * NKS * 64);
    for (int i = tid; i < 2 * NKS * 64; i += 256) Wl[i] = src[i];
  }

  const int wv = tid >> 6, ln = tid & 63;
  const int c = ln & 15, kg = ln >> 4;
  const int arow = wv * 16 + c;        // A-frag row = batch index
  const int rbase = wv * 16 + kg * 4;  // D rows (m89 layout: row=(l>>4)*4+r, col=l&15)
  const int hid = bc * HIDB + (c & 7);
  const bool lo = (c < 8);
  const float bi = bias[hid], bj = bias[Hh + hid];
  const float bff = bias[2 * Hh + hid], bo = bias[3 * Hh + hid];
  float cstate[4] = {0.f, 0.f, 0.f, 0.f};
  int* arr = bar;                      // NBLK arrival slots

  __syncthreads();                      // W in LDS ready

  const short8* W0 = Wl;                // tile0 (gates i,j)
  const short8* W1 = Wl + NKS * 64;     // tile1 (gates f,o)

  f32x4 xa0, xa1;
  // x-part for t=0
  {
    const unsigned short* xr = xT + ((size_t)0 * Bb + arow) * Ee + kg * 8;
    f32x4 a0 = {0.f,0.f,0.f,0.f}, a1 = {0.f,0.f,0.f,0.f};
#pragma unroll 8
    for (int kk = 0; kk < 16; kk++) {
      short8 a = *(const short8*)(xr + kk * 32);
      a0 = __builtin_amdgcn_mfma_f32_16x16x32_bf16(a, W0[kk * 64 + ln], a0, 0, 0, 0);
      a1 = __builtin_amdgcn_mfma_f32_16x16x32_bf16(a, W1[kk * 64 + ln], a1, 0, 0, 0);
    }
    xa0 = a0; xa1 = a1;
  }

  for (int t = 0; t < Tt; t++) {
    const unsigned short* hin = (t & 1) ? hbuf1 : hbuf0;
    unsigned short* hout = (t & 1) ? hbuf0 : hbuf1;

    // ---- h-load burst: 64x8B agent-coherent loads (bypass L1/L2 -> LLC),
    // all issued before first consumption (single latency exposure).
    unsigned long long hv[64];
    const unsigned long long* hq =
        (const unsigned long long*)hin + (size_t)arow * (Hh / 4) + kg * 2;
#pragma unroll
    for (int kk = 0; kk < 32; kk++) {
      hv[2 * kk]     = __hip_atomic_load(hq + kk * 8,     __ATOMIC_RELAXED, __HIP_MEMORY_SCOPE_AGENT);
      hv[2 * kk + 1] = __hip_atomic_load(hq + kk * 8 + 1, __ATOMIC_RELAXED, __HIP_MEMORY_SCOPE_AGENT);
    }

    f32x4 a0 = xa0, a1 = xa1;
#pragma unroll
    for (int kk = 0; kk < 32; kk++) {
      union { unsigned long long q[2]; short8 s; } u;
      u.q[0] = hv[2 * kk]; u.q[1] = hv[2 * kk + 1];
      a0 = __builtin_amdgcn_mfma_f32_16x16x32_bf16(u.s, W0[(16 + kk) * 64 + ln], a0, 0, 0, 0);
      a1 = __builtin_amdgcn_mfma_f32_16x16x32_bf16(u.s, W1[(16 + kk) * 64 + ln], a1, 0, 0, 0);
    }

    // cell update: tile0 lane c<8 holds i (c>=8: j), tile1 holds f (o). One
    // shfl_xor(8) gives each lane all 4 gates; lane pair (c, c^8) redundant.
    float hnew[4];
#pragma unroll
    for (int r = 0; r < 4; r++) {
      const float p0 = a0[r], p1 = a1[r];
      const float s0 = __shfl_xor(p0, 8), s1 = __shfl_xor(p1, 8);
      const float gi = (lo ? p0 : s0) + bi;
      const float gj = (lo ? s0 : p0) + bj;
      const float gf = (lo ? p1 : s1) + bff;
      const float go = (lo ? s1 : p1) + bo;
      const float cn = cstate[r] * fsig(gf + 1.0f) + fsig(gi) * ftanhf(gj);
      cstate[r] = cn;
      hnew[r] = ftanhf(cn) * fsig(go);
    }

    if (t < Tt - 1) {
      // pack pairs (hid even, hid odd) into 4B words via shfl_xor(1); even-lo
      // lanes store agent-coherent (write-through to LLC, nothing dirty in L2).
      unsigned int hw[4];
#pragma unroll
      for (int r = 0; r < 4; r++) {
        unsigned short us = f2bf(hnew[r]);
        unsigned short ps = (unsigned short)__shfl_xor((int)us, 1);
        hw[r] = (unsigned)us | ((unsigned)ps << 16);
      }
      if (lo && !(c & 1)) {
#pragma unroll
        for (int r = 0; r < 4; r++)
          __hip_atomic_store((unsigned int*)hout + (((size_t)(rbase + r) * Hh + hid) >> 1),
                             hw[r], __ATOMIC_RELAXED, __HIP_MEMORY_SCOPE_AGENT);
      }
      __syncthreads();                  // per-wave vmcnt(0): sc stores acked at LLC
      if (tid == 0)                     // relaxed slot store: LLC serializes after h
        __hip_atomic_store(&arr[bc], t + 1, __ATOMIC_RELAXED, __HIP_MEMORY_SCOPE_AGENT);
      // hide barrier latency: x-part MFMAs for t+1 (h-independent, L2-cached)
      {
        const unsigned short* xr = xT + ((size_t)(t + 1) * Bb + arow) * Ee + kg * 8;
        f32x4 b0 = {0.f,0.f,0.f,0.f}, b1 = {0.f,0.f,0.f,0.f};
#pragma unroll 8
        for (int kk = 0; kk < 16; kk++) {
          short8 a = *(const short8*)(xr + kk * 32);
          b0 = __builtin_amdgcn_mfma_f32_16x16x32_bf16(a, W0[kk * 64 + ln], b0, 0, 0, 0);
          b1 = __builtin_amdgcn_mfma_f32_16x16x32_bf16(a, W1[kk * 64 + ln], b1, 0, 0, 0);
        }
        xa0 = b0; xa1 = b1;
      }
      // parallel poll: thread j watches block j's slot (no fences; h is sc-read)
      if (tid < NBLK) {
        while (__hip_atomic_load(&arr[tid], __ATOMIC_RELAXED, __HIP_MEMORY_SCOPE_AGENT) < t + 1)
          __builtin_amdgcn_s_sleep(1);
      }
      asm volatile("" ::: "memory");    // compiler fence: no hoist of next-step loads
      __syncthreads();
    } else {
      if (lo) {
#pragma unroll
        for (int r = 0; r < 4; r++) h_f32[(rbase + r) * Hh + hid] = hnew[r];
      }
    }
  }
}

// ---- classifier: pred = h @ outW + outb, softmax, per-row CE --------------
__global__ __launch_bounds__(256) void classifier_kernel(
    const float* __restrict__ h, const float* __restrict__ outW,
    const float* __restrict__ outb, const float* __restrict__ y,
    float* __restrict__ out, float* __restrict__ losses) {
  __shared__ float red[256];
  const int brow = blockIdx.x;
  const int tid = threadIdx.x;
  const int cc = tid & 31;
  const int part = tid >> 5;
  const float* hr = h + brow * Hh;
  float p = 0.f;
  for (int k = part * 128; k < part * 128 + 128; k++)
    p += hr[k] * outW[k * Cc + cc];
  red[tid] = p;
  __syncthreads();
  if (part < 4) red[tid] += red[tid + 128];
  __syncthreads();
  if (part < 2) red[tid] += red[tid + 64];
  __syncthreads();
  if (part < 1) red[tid] += red[tid + 32];
  __syncthreads();
  if (tid < 32) {
    const float logit = red[tid] + outb[tid];
    float m = logit;
    for (int off = 16; off >= 1; off >>= 1) m = fmaxf(m, __shfl_xor(m, off));
    const float e = __expf(logit - m);
    float s = e;
    for (int off = 16; off >= 1; off >>= 1) s += __shfl_xor(s, off);
    out[brow * Cc + tid] = logit;
    out[Bb * Cc + brow * Cc + tid] = e / s;
    const float logp = (logit - m) - __logf(s);
    float contrib = y[brow * Cc + tid] * logp;
    for (int off = 16; off >= 1; off >>= 1) contrib += __shfl_xor(contrib, off);
    if (tid == 0) losses[brow] = -contrib;
  }
}

__global__ __launch_bounds__(64) void finalize_kernel(const float* __restrict__ losses,
                                                      float* __restrict__ out) {
  float v = losses[threadIdx.x];
  for (int off = 32; off >= 1; off >>= 1) v += __shfl_down(v, off);
  if (threadIdx.x == 0) out[2 * Bb * Cc] = v * (1.0f / Bb);
}

extern "C" void kernel_launch(void* const* d_in, const int* in_sizes, int n_in,
                              void* d_out, int out_size, void* d_ws, size_t ws_size,
                              hipStream_t stream) {
  const float* x    = (const float*)d_in[0];
  const float* y    = (const float*)d_in[1];
  // d_in[2] = seqlen (unused)
  const float* W    = (const float*)d_in[3];
  const float* bias = (const float*)d_in[4];
  const float* outW = (const float*)d_in[5];
  const float* outb = (const float*)d_in[6];
  float* out = (float*)d_out;

  char* wsp = (char*)d_ws;
  size_t off = 0;
  auto walloc = [&](size_t bytes) -> void* {
    void* p = wsp + off;
    off += (bytes + 255) & ~(size_t)255;
    return p;
  };
  unsigned short* xT   = (unsigned short*)walloc((size_t)Bb * Tt * Ee * 2);       // 32 MiB
  unsigned short* Wpk  = (unsigned short*)walloc((size_t)NBLK * 2 * NKS * 64 * 16); // 12 MiB
  unsigned short* hbf0 = (unsigned short*)walloc((size_t)Bb * Hh * 2);
  unsigned short* hbf1 = (unsigned short*)walloc((size_t)Bb * Hh * 2);
  float* hf     = (float*)walloc((size_t)Bb * Hh * 4);
  float* losses = (float*)walloc(256);
  int* bar      = (int*)walloc(1024);
  (void)ws_size; (void)in_sizes; (void)n_in; (void)out_size;

  transpose_x_kernel<<<Bb * Tt, 256, 0, stream>>>(x, xT);
  pack_w_kernel<<<NBLK * 2 * NKS, 64, 0, stream>>>(W, Wpk);
  init_state_kernel<<<(Bb * Hh) / 256, 256, 0, stream>>>(hbf0, bar);

  lstm_persist<<<NBLK, 256, 0, stream>>>(xT, Wpk, bias, hbf0, hbf1, hf, bar);

  classifier_kernel<<<Bb, 256, 0, stream>>>(hf, outW, outb, y, out, losses);
  finalize_kernel<<<1, 64, 0, stream>>>(losses, out);
}

// Round 3
// 4964.862 us; speedup vs baseline: 1.8162x; 1.1786x over previous
//
#include <hip/hip_runtime.h>
#include <hip/hip_bf16.h>

// SentenceClassifier: LSTM(B=64,T=512,E=512,H=1024) -> h_T @ outW + outb -> softmax/CE
// Persistent-kernel design: 128 blocks x 256 thr, one block per 8 hidden units
// (32 gate cols = 2 MFMA col-tiles, W slice 96KB in LDS). Internal t-loop with
// per-block arrival slots + parallel poll; fence-free.
// h exchange: ROTATING COLD BUFFERS (one 128KB buffer per step, 64MiB total).
// Writers store agent-scope write-through (LLC). Readers use PLAIN CACHED
// short8 loads: the address was never in any L2 (cold), so the post-barrier
// read must miss L2 and fetch the fresh data from LLC -- no buffer_inv, no
// 8B-granule uncached request storm (R2's bottleneck: 2.1M 8B LLC transactions
// per step). 16 blocks/XCD now share one 128KB L2 fill per step.
// x-part MFMAs for t+1 computed between barrier-arrive and spin.

#define Bb 64
#define Tt 512
#define Ee 512
#define Hh 1024
#define Cc 32
#define G4 4096
#define NKS 48     // (E+H)/32
#define NBLK 128
#define HIDB 8     // hid units per block

typedef __attribute__((ext_vector_type(8))) short short8;
typedef __attribute__((ext_vector_type(4))) float f32x4;

__device__ __forceinline__ unsigned short f2bf(float f) {
  __hip_bfloat16 h = __float2bfloat16(f);
  union { __hip_bfloat16 h; unsigned short u; } cv; cv.h = h; return cv.u;
}
static __device__ __forceinline__ float fsig(float x) { return 1.0f / (1.0f + __expf(-x)); }
static __device__ __forceinline__ float ftanhf(float x) {
  float e = __expf(-2.0f * fabsf(x));
  float t = (1.0f - e) / (1.0f + e);
  return copysignf(t, x);
}

// ---- x [B,T,E] f32 -> xT [T,B,E] bf16 (contiguous 64KB window per step) ----
__global__ __launch_bounds__(256) void transpose_x_kernel(const float* __restrict__ x,
                                                          unsigned short* __restrict__ xT) {
  const int bid = blockIdx.x;          // row*Tt + t
  const int row = bid >> 9, t = bid & (Tt - 1);
  const int e = threadIdx.x * 2;
  const float* src = x + ((size_t)row * Tt + t) * Ee + e;
  float2 v = *(const float2*)src;
  ushort2 o; o.x = f2bf(v.x); o.y = f2bf(v.y);
  *(ushort2*)(xT + ((size_t)t * Bb + row) * Ee + e) = o;
}

// ---- W [1536,4096] f32 -> per-block B-frag-packed bf16 --------------------
__global__ __launch_bounds__(64) void pack_w_kernel(const float* __restrict__ W,
                                                    unsigned short* __restrict__ Wpk) {
  const int fid = blockIdx.x;          // blk*96 + tau*48 + ks
  const int l = threadIdx.x;
  const int blk = fid / 96, rem = fid % 96;
  const int tau = rem / 48, ks = rem % 48;
  const int c = l & 15;
  const int col = (2 * tau + (c >> 3)) * Hh + blk * HIDB + (c & 7);
  const int k0 = ks * 32 + (l >> 4) * 8;
  short8 v;
#pragma unroll
  for (int i = 0; i < 8; i++) v[i] = (short)f2bf(W[(size_t)(k0 + i) * G4 + col]);
  *(short8*)(Wpk + ((size_t)fid * 64 + l) * 8) = v;
}

// ---- zero h buffer 0 + barrier state --------------------------------------
__global__ __launch_bounds__(256) void init_state_kernel(unsigned short* __restrict__ h0,
                                                         int* __restrict__ bar) {
  int i = blockIdx.x * 256 + threadIdx.x;   // grid covers Bb*Hh
  h0[i] = 0;
  if (i < NBLK) bar[i] = 0;                 // per-block arrival slots
}

// ---- persistent LSTM kernel ----------------------------------------------
__global__ __launch_bounds__(256, 1) void lstm_persist(
    const unsigned short* __restrict__ xT, const unsigned short* __restrict__ Wpk,
    const float* __restrict__ bias,
    unsigned short* __restrict__ hseq,   // Tt buffers of Bb*Hh bf16 (rotating, cold)
    float* __restrict__ h_f32, int* __restrict__ bar) {
  __shared__ short8 Wl[2 * NKS * 64];       // 96 KiB
  const int bc = blockIdx.x;
  const int tid = threadIdx.x;

  { // one-time: W slice -> LDS (linear 96KB copy)
    const short8* src = (const short8*)Wpk + (size_t)bc * (2 * NKS * 64);
    for (int i = tid; i < 2 * NKS * 64; i += 256) Wl[i] = src[i];
  }

  const int wv = tid >> 6, ln = tid & 63;
  const int c = ln & 15, kg = ln >> 4;
  const int arow = wv * 16 + c;        // A-frag row = batch index
  const int rbase = wv * 16 + kg * 4;  // D rows (m89 layout: row=(l>>4)*4+r, col=l&15)
  const int hid = bc * HIDB + (c & 7);
  const bool lo = (c < 8);
  const float bi = bias[hid], bj = bias[Hh + hid];
  const float bff = bias[2 * Hh + hid], bo = bias[3 * Hh + hid];
  float cstate[4] = {0.f, 0.f, 0.f, 0.f};
  int* arr = bar;                      // NBLK arrival slots

  __syncthreads();                      // W in LDS ready

  const short8* W0 = Wl;                // tile0 (gates i,j)
  const short8* W1 = Wl + NKS * 64;     // tile1 (gates f,o)

  f32x4 xa0, xa1;
  // x-part for t=0
  {
    const unsigned short* xr = xT + ((size_t)0 * Bb + arow) * Ee + kg * 8;
    f32x4 a0 = {0.f,0.f,0.f,0.f}, a1 = {0.f,0.f,0.f,0.f};
#pragma unroll 8
    for (int kk = 0; kk < 16; kk++) {
      short8 a = *(const short8*)(xr + kk * 32);
      a0 = __builtin_amdgcn_mfma_f32_16x16x32_bf16(a, W0[kk * 64 + ln], a0, 0, 0, 0);
      a1 = __builtin_amdgcn_mfma_f32_16x16x32_bf16(a, W1[kk * 64 + ln], a1, 0, 0, 0);
    }
    xa0 = a0; xa1 = a1;
  }

  for (int t = 0; t < Tt; t++) {
    // step t input = buffer t (cold address: never L2-cached before its data
    // arrived in LLC via write-through, so plain cached loads are safe+fast)
    const unsigned short* hin = hseq + (size_t)t * (Bb * Hh);
    unsigned short* hout = (unsigned short*)hseq + (size_t)(t + 1) * (Bb * Hh);

    f32x4 a0 = xa0, a1 = xa1;
    const unsigned short* hr = hin + (size_t)arow * Hh + kg * 8;
#pragma unroll 8
    for (int kk = 0; kk < 32; kk++) {
      short8 a = *(const short8*)(hr + kk * 32);
      a0 = __builtin_amdgcn_mfma_f32_16x16x32_bf16(a, W0[(16 + kk) * 64 + ln], a0, 0, 0, 0);
      a1 = __builtin_amdgcn_mfma_f32_16x16x32_bf16(a, W1[(16 + kk) * 64 + ln], a1, 0, 0, 0);
    }

    // cell update: tile0 lane c<8 holds i (c>=8: j), tile1 holds f (o). One
    // shfl_xor(8) gives each lane all 4 gates; lane pair (c, c^8) redundant.
    float hnew[4];
#pragma unroll
    for (int r = 0; r < 4; r++) {
      const float p0 = a0[r], p1 = a1[r];
      const float s0 = __shfl_xor(p0, 8), s1 = __shfl_xor(p1, 8);
      const float gi = (lo ? p0 : s0) + bi;
      const float gj = (lo ? s0 : p0) + bj;
      const float gf = (lo ? p1 : s1) + bff;
      const float go = (lo ? s1 : p1) + bo;
      const float cn = cstate[r] * fsig(gf + 1.0f) + fsig(gi) * ftanhf(gj);
      cstate[r] = cn;
      hnew[r] = ftanhf(cn) * fsig(go);
    }

    if (t < Tt - 1) {
      // pack pairs (hid even, hid odd) into 4B words via shfl_xor(1); even-lo
      // lanes store agent-coherent (write-through to LLC, nothing dirty in L2).
      unsigned int hw[4];
#pragma unroll
      for (int r = 0; r < 4; r++) {
        unsigned short us = f2bf(hnew[r]);
        unsigned short ps = (unsigned short)__shfl_xor((int)us, 1);
        hw[r] = (unsigned)us | ((unsigned)ps << 16);
      }
      if (lo && !(c & 1)) {
#pragma unroll
        for (int r = 0; r < 4; r++)
          __hip_atomic_store((unsigned int*)hout + (((size_t)(rbase + r) * Hh + hid) >> 1),
                             hw[r], __ATOMIC_RELAXED, __HIP_MEMORY_SCOPE_AGENT);
      }
      __syncthreads();                  // per-wave vmcnt(0): sc stores acked at LLC
      if (tid == 0)                     // relaxed slot store: LLC serializes after h
        __hip_atomic_store(&arr[bc], t + 1, __ATOMIC_RELAXED, __HIP_MEMORY_SCOPE_AGENT);
      // hide barrier latency: x-part MFMAs for t+1 (h-independent, L2-cached)
      {
        const unsigned short* xr = xT + ((size_t)(t + 1) * Bb + arow) * Ee + kg * 8;
        f32x4 b0 = {0.f,0.f,0.f,0.f}, b1 = {0.f,0.f,0.f,0.f};
#pragma unroll 8
        for (int kk = 0; kk < 16; kk++) {
          short8 a = *(const short8*)(xr + kk * 32);
          b0 = __builtin_amdgcn_mfma_f32_16x16x32_bf16(a, W0[kk * 64 + ln], b0, 0, 0, 0);
          b1 = __builtin_amdgcn_mfma_f32_16x16x32_bf16(a, W1[kk * 64 + ln], b1, 0, 0, 0);
        }
        xa0 = b0; xa1 = b1;
      }
      // parallel poll: thread j watches block j's slot (no fences; h reads are
      // cold-address cached loads, slot reads are agent-scope)
      if (tid < NBLK) {
        while (__hip_atomic_load(&arr[tid], __ATOMIC_RELAXED, __HIP_MEMORY_SCOPE_AGENT) < t + 1)
          __builtin_amdgcn_s_sleep(1);
      }
      asm volatile("" ::: "memory");    // compiler fence: no hoist of next-step loads
      __syncthreads();
    } else {
      if (lo) {
#pragma unroll
        for (int r = 0; r < 4; r++) h_f32[(rbase + r) * Hh + hid] = hnew[r];
      }
    }
  }
}

// ---- classifier: pred = h @ outW + outb, softmax, per-row CE --------------
__global__ __launch_bounds__(256) void classifier_kernel(
    const float* __restrict__ h, const float* __restrict__ outW,
    const float* __restrict__ outb, const float* __restrict__ y,
    float* __restrict__ out, float* __restrict__ losses) {
  __shared__ float red[256];
  const int brow = blockIdx.x;
  const int tid = threadIdx.x;
  const int cc = tid & 31;
  const int part = tid >> 5;
  const float* hr = h + brow * Hh;
  float p = 0.f;
  for (int k = part * 128; k < part * 128 + 128; k++)
    p += hr[k] * outW[k * Cc + cc];
  red[tid] = p;
  __syncthreads();
  if (part < 4) red[tid] += red[tid + 128];
  __syncthreads();
  if (part < 2) red[tid] += red[tid + 64];
  __syncthreads();
  if (part < 1) red[tid] += red[tid + 32];
  __syncthreads();
  if (tid < 32) {
    const float logit = red[tid] + outb[tid];
    float m = logit;
    for (int off = 16; off >= 1; off >>= 1) m = fmaxf(m, __shfl_xor(m, off));
    const float e = __expf(logit - m);
    float s = e;
    for (int off = 16; off >= 1; off >>= 1) s += __shfl_xor(s, off);
    out[brow * Cc + tid] = logit;
    out[Bb * Cc + brow * Cc + tid] = e / s;
    const float logp = (logit - m) - __logf(s);
    float contrib = y[brow * Cc + tid] * logp;
    for (int off = 16; off >= 1; off >>= 1) contrib += __shfl_xor(contrib, off);
    if (tid == 0) losses[brow] = -contrib;
  }
}

__global__ __launch_bounds__(64) void finalize_kernel(const float* __restrict__ losses,
                                                      float* __restrict__ out) {
  float v = losses[threadIdx.x];
  for (int off = 32; off >= 1; off >>= 1) v += __shfl_down(v, off);
  if (threadIdx.x == 0) out[2 * Bb * Cc] = v * (1.0f / Bb);
}

extern "C" void kernel_launch(void* const* d_in, const int* in_sizes, int n_in,
                              void* d_out, int out_size, void* d_ws, size_t ws_size,
                              hipStream_t stream) {
  const float* x    = (const float*)d_in[0];
  const float* y    = (const float*)d_in[1];
  // d_in[2] = seqlen (unused)
  const float* W    = (const float*)d_in[3];
  const float* bias = (const float*)d_in[4];
  const float* outW = (const float*)d_in[5];
  const float* outb = (const float*)d_in[6];
  float* out = (float*)d_out;

  char* wsp = (char*)d_ws;
  size_t off = 0;
  auto walloc = [&](size_t bytes) -> void* {
    void* p = wsp + off;
    off += (bytes + 255) & ~(size_t)255;
    return p;
  };
  unsigned short* xT   = (unsigned short*)walloc((size_t)Bb * Tt * Ee * 2);         // 32 MiB
  unsigned short* Wpk  = (unsigned short*)walloc((size_t)NBLK * 2 * NKS * 64 * 16); // 12 MiB
  unsigned short* hseq = (unsigned short*)walloc((size_t)Tt * Bb * Hh * 2);         // 64 MiB rotating h
  float* hf     = (float*)walloc((size_t)Bb * Hh * 4);
  float* losses = (float*)walloc(256);
  int* bar      = (int*)walloc(1024);
  (void)ws_size; (void)in_sizes; (void)n_in; (void)out_size;

  transpose_x_kernel<<<Bb * Tt, 256, 0, stream>>>(x, xT);
  pack_w_kernel<<<NBLK * 2 * NKS, 64, 0, stream>>>(W, Wpk);
  init_state_kernel<<<(Bb * Hh) / 256, 256, 0, stream>>>(hseq, bar);

  lstm_persist<<<NBLK, 256, 0, stream>>>(xT, Wpk, bias, hseq, hf, bar);

  classifier_kernel<<<Bb, 256, 0, stream>>>(hf, outW, outb, y, out, losses);
  finalize_kernel<<<1, 64, 0, stream>>>(losses, out);
}

// Round 4
// 4838.793 us; speedup vs baseline: 1.8635x; 1.0261x over previous
//
#include <hip/hip_runtime.h>
#include <hip/hip_bf16.h>

// SentenceClassifier: LSTM(B=64,T=512,E=512,H=1024) -> h_T @ outW + outb -> softmax/CE
// Persistent-kernel, 128 blocks x 256 thr, block owns 8 hidden units (32 gate
// cols, W slice 96KB LDS). R4: WAVE-AUTONOMOUS pipelines -- wave w (rows
// [16w,16w+16)) syncs only with wave w of other blocks via per-(block,wave)
// flags; NO __syncthreads in the t-loop. h exchange: rotating cold buffers
// (64MiB), BLOCK-MAJOR layout hseq[t][bc][row][8hid] so each (block,wave)
// writes a private contiguous 256B (exclusive LLC lines, no partial-line
// sharing) and consumers read contiguous 16B cached loads. Writers store
// agent-scope write-through (LLC); readers use plain cached loads on cold
// addresses (never L2-cached before data reached LLC). Flags padded to 128B.
// x-part MFMAs for t+1 computed between flag-store and poll.

#define Bb 64
#define Tt 512
#define Ee 512
#define Hh 1024
#define Cc 32
#define G4 4096
#define NKS 48     // (E+H)/32
#define NBLK 128
#define HIDB 8     // hid units per block
#define FPAD 32    // flag slot pad (ints) = 128B

typedef __attribute__((ext_vector_type(8))) short short8;
typedef __attribute__((ext_vector_type(4))) float f32x4;

__device__ __forceinline__ unsigned short f2bf(float f) {
  __hip_bfloat16 h = __float2bfloat16(f);
  union { __hip_bfloat16 h; unsigned short u; } cv; cv.h = h; return cv.u;
}
static __device__ __forceinline__ float fsig(float x) { return 1.0f / (1.0f + __expf(-x)); }
static __device__ __forceinline__ float ftanhf(float x) {
  float e = __expf(-2.0f * fabsf(x));
  float t = (1.0f - e) / (1.0f + e);
  return copysignf(t, x);
}

// ---- x [B,T,E] f32 -> xT [T,B,E] bf16 (contiguous 64KB window per step) ----
__global__ __launch_bounds__(256) void transpose_x_kernel(const float* __restrict__ x,
                                                          unsigned short* __restrict__ xT) {
  const int bid = blockIdx.x;          // row*Tt + t
  const int row = bid >> 9, t = bid & (Tt - 1);
  const int e = threadIdx.x * 2;
  const float* src = x + ((size_t)row * Tt + t) * Ee + e;
  float2 v = *(const float2*)src;
  ushort2 o; o.x = f2bf(v.x); o.y = f2bf(v.y);
  *(ushort2*)(xT + ((size_t)t * Bb + row) * Ee + e) = o;
}

// ---- W [1536,4096] f32 -> per-block B-frag-packed bf16 --------------------
__global__ __launch_bounds__(64) void pack_w_kernel(const float* __restrict__ W,
                                                    unsigned short* __restrict__ Wpk) {
  const int fid = blockIdx.x;          // blk*96 + tau*48 + ks
  const int l = threadIdx.x;
  const int blk = fid / 96, rem = fid % 96;
  const int tau = rem / 48, ks = rem % 48;
  const int c = l & 15;
  const int col = (2 * tau + (c >> 3)) * Hh + blk * HIDB + (c & 7);
  const int k0 = ks * 32 + (l >> 4) * 8;
  short8 v;
#pragma unroll
  for (int i = 0; i < 8; i++) v[i] = (short)f2bf(W[(size_t)(k0 + i) * G4 + col]);
  *(short8*)(Wpk + ((size_t)fid * 64 + l) * 8) = v;
}

// ---- zero h buffer 0 + flag state -----------------------------------------
__global__ __launch_bounds__(256) void init_state_kernel(unsigned short* __restrict__ h0,
                                                         int* __restrict__ flg) {
  int i = blockIdx.x * 256 + threadIdx.x;   // grid covers Bb*Hh
  h0[i] = 0;
  if (i < 4 * NBLK * FPAD) flg[i] = 0;      // 512 padded flag slots
}

// ---- persistent LSTM kernel ----------------------------------------------
__global__ __launch_bounds__(256, 1) void lstm_persist(
    const unsigned short* __restrict__ xT, const unsigned short* __restrict__ Wpk,
    const float* __restrict__ bias,
    unsigned short* __restrict__ hseq,   // Tt+1 buffers, block-major [bc][row][8hid]
    float* __restrict__ h_f32, int* __restrict__ flg) {
  __shared__ short8 Wl[2 * NKS * 64];       // 96 KiB
  const int bc = blockIdx.x;
  const int tid = threadIdx.x;

  { // one-time: W slice -> LDS (linear 96KB copy)
    const short8* src = (const short8*)Wpk + (size_t)bc * (2 * NKS * 64);
    for (int i = tid; i < 2 * NKS * 64; i += 256) Wl[i] = src[i];
  }

  const int wv = tid >> 6, ln = tid & 63;
  const int c = ln & 15, kg = ln >> 4;
  const int arow = wv * 16 + c;        // A-frag row = batch index
  const int rbase = wv * 16 + kg * 4;  // D rows (m89 layout: row=(l>>4)*4+r, col=l&15)
  const int hid = bc * HIDB + (c & 7);
  const bool lo = (c < 8);
  const float bi = bias[hid], bj = bias[Hh + hid];
  const float bff = bias[2 * Hh + hid], bo = bias[3 * Hh + hid];
  float cstate[4] = {0.f, 0.f, 0.f, 0.f};

  __syncthreads();                      // W in LDS ready (only barrier in kernel)

  const short8* W0 = Wl;                // tile0 (gates i,j)
  const short8* W1 = Wl + NKS * 64;     // tile1 (gates f,o)

  // wave's poll slots: wave wv needs wave wv of all 128 blocks; 2 slots/lane
  int* slot0 = flg + (wv * NBLK + ln) * FPAD;
  int* slot1 = flg + (wv * NBLK + ln + 64) * FPAD;
  int* myslot = flg + (wv * NBLK + bc) * FPAD;

  f32x4 xa0, xa1;
  // x-part for t=0
  {
    const unsigned short* xr = xT + ((size_t)0 * Bb + arow) * Ee + kg * 8;
    f32x4 a0 = {0.f,0.f,0.f,0.f}, a1 = {0.f,0.f,0.f,0.f};
#pragma unroll 8
    for (int kk = 0; kk < 16; kk++) {
      short8 a = *(const short8*)(xr + kk * 32);
      a0 = __builtin_amdgcn_mfma_f32_16x16x32_bf16(a, W0[kk * 64 + ln], a0, 0, 0, 0);
      a1 = __builtin_amdgcn_mfma_f32_16x16x32_bf16(a, W1[kk * 64 + ln], a1, 0, 0, 0);
    }
    xa0 = a0; xa1 = a1;
  }

  for (int t = 0; t < Tt; t++) {
    // ---- consume hseq[t], block-major: hid chunk of MFMA k-step kk at
    // producer block (kk*4+kg); lane reads contiguous 16B at [bsrc][arow][0..8)
    const unsigned short* hr = hseq + (size_t)t * (NBLK * Bb * HIDB) + kg * 512 + arow * 8;
    f32x4 a0 = xa0, a1 = xa1;
#pragma unroll 8
    for (int kk = 0; kk < 32; kk++) {
      short8 a = *(const short8*)(hr + kk * 2048);
      a0 = __builtin_amdgcn_mfma_f32_16x16x32_bf16(a, W0[(16 + kk) * 64 + ln], a0, 0, 0, 0);
      a1 = __builtin_amdgcn_mfma_f32_16x16x32_bf16(a, W1[(16 + kk) * 64 + ln], a1, 0, 0, 0);
    }

    // cell update: tile0 lane c<8 holds i (c>=8: j), tile1 holds f (o). One
    // shfl_xor(8) gives each lane all 4 gates; lane pair (c, c^8) redundant.
    float hnew[4];
#pragma unroll
    for (int r = 0; r < 4; r++) {
      const float p0 = a0[r], p1 = a1[r];
      const float s0 = __shfl_xor(p0, 8), s1 = __shfl_xor(p1, 8);
      const float gi = (lo ? p0 : s0) + bi;
      const float gj = (lo ? s0 : p0) + bj;
      const float gf = (lo ? p1 : s1) + bff;
      const float go = (lo ? s1 : p1) + bo;
      const float cn = cstate[r] * fsig(gf + 1.0f) + fsig(gi) * ftanhf(gj);
      cstate[r] = cn;
      hnew[r] = ftanhf(cn) * fsig(go);
    }

    if (t < Tt - 1) {
      // pack hid pairs into 4B words; even-lo lanes store agent-coherent
      // (write-through to LLC). Block-major: wave writes private 256B.
      unsigned int hw[4];
#pragma unroll
      for (int r = 0; r < 4; r++) {
        unsigned short us = f2bf(hnew[r]);
        unsigned short ps = (unsigned short)__shfl_xor((int)us, 1);
        hw[r] = (unsigned)us | ((unsigned)ps << 16);
      }
      unsigned int* hob = (unsigned int*)hseq + (size_t)(t + 1) * (NBLK * Bb * HIDB / 2)
                          + bc * (Bb * HIDB / 2);
      if (lo && !(c & 1)) {
#pragma unroll
        for (int r = 0; r < 4; r++)
          __hip_atomic_store(hob + (rbase + r) * 4 + ((c & 7) >> 1),
                             hw[r], __ATOMIC_RELAXED, __HIP_MEMORY_SCOPE_AGENT);
      }
      // wave-local drain: h stores acked at coherence point before flag store
      asm volatile("s_waitcnt vmcnt(0)" ::: "memory");
      if (ln == 0)
        __hip_atomic_store(myslot, t + 1, __ATOMIC_RELAXED, __HIP_MEMORY_SCOPE_AGENT);
      // hide sync latency: x-part MFMAs for t+1 (h-independent, L2-cached)
      {
        const unsigned short* xr = xT + ((size_t)(t + 1) * Bb + arow) * Ee + kg * 8;
        f32x4 b0 = {0.f,0.f,0.f,0.f}, b1 = {0.f,0.f,0.f,0.f};
#pragma unroll 8
        for (int kk = 0; kk < 16; kk++) {
          short8 a = *(const short8*)(xr + kk * 32);
          b0 = __builtin_amdgcn_mfma_f32_16x16x32_bf16(a, W0[kk * 64 + ln], b0, 0, 0, 0);
          b1 = __builtin_amdgcn_mfma_f32_16x16x32_bf16(a, W1[kk * 64 + ln], b1, 0, 0, 0);
        }
        xa0 = b0; xa1 = b1;
      }
      // poll own wave's domain: 128 slots, 2 per lane (padded to 128B each)
      for (;;) {
        int v0 = __hip_atomic_load(slot0, __ATOMIC_RELAXED, __HIP_MEMORY_SCOPE_AGENT);
        int v1 = __hip_atomic_load(slot1, __ATOMIC_RELAXED, __HIP_MEMORY_SCOPE_AGENT);
        if (v0 > t && v1 > t) break;
        __builtin_amdgcn_s_sleep(1);
      }
      asm volatile("" ::: "memory");    // no hoist of next-step h loads above poll
    } else {
      if (lo) {
#pragma unroll
        for (int r = 0; r < 4; r++) h_f32[(rbase + r) * Hh + hid] = hnew[r];
      }
    }
  }
}

// ---- classifier: pred = h @ outW + outb, softmax, per-row CE --------------
__global__ __launch_bounds__(256) void classifier_kernel(
    const float* __restrict__ h, const float* __restrict__ outW,
    const float* __restrict__ outb, const float* __restrict__ y,
    float* __restrict__ out, float* __restrict__ losses) {
  __shared__ float red[256];
  const int brow = blockIdx.x;
  const int tid = threadIdx.x;
  const int cc = tid & 31;
  const int part = tid >> 5;
  const float* hr = h + brow * Hh;
  float p = 0.f;
  for (int k = part * 128; k < part * 128 + 128; k++)
    p += hr[k] * outW[k * Cc + cc];
  red[tid] = p;
  __syncthreads();
  if (part < 4) red[tid] += red[tid + 128];
  __syncthreads();
  if (part < 2) red[tid] += red[tid + 64];
  __syncthreads();
  if (part < 1) red[tid] += red[tid + 32];
  __syncthreads();
  if (tid < 32) {
    const float logit = red[tid] + outb[tid];
    float m = logit;
    for (int off = 16; off >= 1; off >>= 1) m = fmaxf(m, __shfl_xor(m, off));
    const float e = __expf(logit - m);
    float s = e;
    for (int off = 16; off >= 1; off >>= 1) s += __shfl_xor(s, off);
    out[brow * Cc + tid] = logit;
    out[Bb * Cc + brow * Cc + tid] = e / s;
    const float logp = (logit - m) - __logf(s);
    float contrib = y[brow * Cc + tid] * logp;
    for (int off = 16; off >= 1; off >>= 1) contrib += __shfl_xor(contrib, off);
    if (tid == 0) losses[brow] = -contrib;
  }
}

__global__ __launch_bounds__(64) void finalize_kernel(const float* __restrict__ losses,
                                                      float* __restrict__ out) {
  float v = losses[threadIdx.x];
  for (int off = 32; off >= 1; off >>= 1) v += __shfl_down(v, off);
  if (threadIdx.x == 0) out[2 * Bb * Cc] = v * (1.0f / Bb);
}

extern "C" void kernel_launch(void* const* d_in, const int* in_sizes, int n_in,
                              void* d_out, int out_size, void* d_ws, size_t ws_size,
                              hipStream_t stream) {
  const float* x    = (const float*)d_in[0];
  const float* y    = (const float*)d_in[1];
  // d_in[2] = seqlen (unused)
  const float* W    = (const float*)d_in[3];
  const float* bias = (const float*)d_in[4];
  const float* outW = (const float*)d_in[5];
  const float* outb = (const float*)d_in[6];
  float* out = (float*)d_out;

  char* wsp = (char*)d_ws;
  size_t off = 0;
  auto walloc = [&](size_t bytes) -> void* {
    void* p = wsp + off;
    off += (bytes + 255) & ~(size_t)255;
    return p;
  };
  unsigned short* xT   = (unsigned short*)walloc((size_t)Bb * Tt * Ee * 2);         // 32 MiB
  unsigned short* Wpk  = (unsigned short*)walloc((size_t)NBLK * 2 * NKS * 64 * 16); // 12 MiB
  unsigned short* hseq = (unsigned short*)walloc((size_t)Tt * Bb * Hh * 2);         // 64 MiB rotating h
  float* hf     = (float*)walloc((size_t)Bb * Hh * 4);
  float* losses = (float*)walloc(256);
  int* flg      = (int*)walloc(4 * NBLK * FPAD * 4);                                // 64 KiB flags
  (void)ws_size; (void)in_sizes; (void)n_in; (void)out_size;

  transpose_x_kernel<<<Bb * Tt, 256, 0, stream>>>(x, xT);
  pack_w_kernel<<<NBLK * 2 * NKS, 64, 0, stream>>>(W, Wpk);
  init_state_kernel<<<(Bb * Hh) / 256, 256, 0, stream>>>(hseq, flg);

  lstm_persist<<<NBLK, 256, 0, stream>>>(xT, Wpk, bias, hseq, hf, flg);

  classifier_kernel<<<Bb, 256, 0, stream>>>(hf, outW, outb, y, out, losses);
  finalize_kernel<<<1, 64, 0, stream>>>(losses, out);
}

// Round 6
// 3969.941 us; speedup vs baseline: 2.2713x; 1.2189x over previous
//
#include <hip/hip_runtime.h>
#include <hip/hip_bf16.h>

// SentenceClassifier: LSTM(B=64,T=512,E=512,H=1024) -> h_T @ outW + outb -> softmax/CE
// Persistent-kernel, 128 blocks x 256 thr, block owns 8 hidden units (32 gate
// cols, W slice 96KB LDS). R5: PIPELINED PER-GROUP CONSUMPTION -- a wave's
// h-GEMM k-slice kk needs only producer blocks 4kk..4kk+3, so readiness is
// gated per GROUP of 4 kk (16 producer blocks), software-pipelined with A/B
// fragment buffers: wait(g) -> load(g) -> MFMA(g-1). Removes the all-or-
// nothing barrier semantics whose max-of-128 skew + synchronized 16MB read
// burst dominated R3/R4 (~9.5us/step vs ~3us chain model). h: rotating cold
// buffers (64MiB), block-major [bc][row][8hid]; producers store agent-scope
// write-through (LLC) then vmcnt(0)+flag; consumers use plain cached 16B
// loads on cold addresses after the group's flags confirm LLC arrival.
// No __syncthreads in the t-loop. x-part MFMAs for t+1 after flag store.

#define Bb 64
#define Tt 512
#define Ee 512
#define Hh 1024
#define Cc 32
#define G4 4096
#define NKS 48     // (E+H)/32
#define NBLK 128
#define HIDB 8     // hid units per block
#define FPAD 32    // flag slot pad (ints) = 128B

typedef __attribute__((ext_vector_type(8))) short short8;
typedef __attribute__((ext_vector_type(4))) float f32x4;

__device__ __forceinline__ unsigned short f2bf(float f) {
  __hip_bfloat16 h = __float2bfloat16(f);
  union { __hip_bfloat16 h; unsigned short u; } cv; cv.h = h; return cv.u;
}
static __device__ __forceinline__ float fsig(float x) { return 1.0f / (1.0f + __expf(-x)); }
static __device__ __forceinline__ float ftanhf(float x) {
  float e = __expf(-2.0f * fabsf(x));
  float t = (1.0f - e) / (1.0f + e);
  return copysignf(t, x);
}

// ---- x [B,T,E] f32 -> xT [T,B,E] bf16 (contiguous 64KB window per step) ----
__global__ __launch_bounds__(256) void transpose_x_kernel(const float* __restrict__ x,
                                                          unsigned short* __restrict__ xT) {
  const int bid = blockIdx.x;          // row*Tt + t
  const int row = bid >> 9, t = bid & (Tt - 1);
  const int e = threadIdx.x * 2;
  const float* src = x + ((size_t)row * Tt + t) * Ee + e;
  float2 v = *(const float2*)src;
  ushort2 o; o.x = f2bf(v.x); o.y = f2bf(v.y);
  *(ushort2*)(xT + ((size_t)t * Bb + row) * Ee + e) = o;
}

// ---- W [1536,4096] f32 -> per-block B-frag-packed bf16 --------------------
__global__ __launch_bounds__(64) void pack_w_kernel(const float* __restrict__ W,
                                                    unsigned short* __restrict__ Wpk) {
  const int fid = blockIdx.x;          // blk*96 + tau*48 + ks
  const int l = threadIdx.x;
  const int blk = fid / 96, rem = fid % 96;
  const int tau = rem / 48, ks = rem % 48;
  const int c = l & 15;
  const int col = (2 * tau + (c >> 3)) * Hh + blk * HIDB + (c & 7);
  const int k0 = ks * 32 + (l >> 4) * 8;
  short8 v;
#pragma unroll
  for (int i = 0; i < 8; i++) v[i] = (short)f2bf(W[(size_t)(k0 + i) * G4 + col]);
  *(short8*)(Wpk + ((size_t)fid * 64 + l) * 8) = v;
}

// ---- zero h buffer 0 + flag state -----------------------------------------
__global__ __launch_bounds__(256) void init_state_kernel(unsigned short* __restrict__ h0,
                                                         int* __restrict__ flg) {
  int i = blockIdx.x * 256 + threadIdx.x;   // grid covers Bb*Hh
  h0[i] = 0;
  if (i < 4 * NBLK * FPAD) flg[i] = 0;      // 512 padded flag slots
}

// ---- persistent LSTM kernel ----------------------------------------------
__global__ __launch_bounds__(256, 1) void lstm_persist(
    const unsigned short* __restrict__ xT, const unsigned short* __restrict__ Wpk,
    const float* __restrict__ bias,
    unsigned short* __restrict__ hseq,   // Tt buffers, block-major [bc][row][8hid]
    float* __restrict__ h_f32, int* __restrict__ flg) {
  __shared__ short8 Wl[2 * NKS * 64];       // 96 KiB
  const int bc = blockIdx.x;
  const int tid = threadIdx.x;

  { // one-time: W slice -> LDS (linear 96KB copy)
    const short8* src = (const short8*)Wpk + (size_t)bc * (2 * NKS * 64);
    for (int i = tid; i < 2 * NKS * 64; i += 256) Wl[i] = src[i];
  }

  const int wv = tid >> 6, ln = tid & 63;
  const int c = ln & 15, kg = ln >> 4;
  const int arow = wv * 16 + c;        // A-frag row = batch index
  const int rbase = wv * 16 + kg * 4;  // D rows (m89 layout: row=(l>>4)*4+r, col=l&15)
  const int hid = bc * HIDB + (c & 7);
  const bool lo = (c < 8);
  const float bi = bias[hid], bj = bias[Hh + hid];
  const float bff = bias[2 * Hh + hid], bo = bias[3 * Hh + hid];
  float cstate[4] = {0.f, 0.f, 0.f, 0.f};

  __syncthreads();                      // W in LDS ready (only barrier in kernel)

  const short8* W0 = Wl;                // tile0 (gates i,j)
  const short8* W1 = Wl + NKS * 64;     // tile1 (gates f,o)

  int* flgw = flg + wv * NBLK * FPAD;   // own wave's flag domain
  int* myslot = flgw + bc * FPAD;

  f32x4 xa0, xa1;
  // x-part for t=0
  {
    const unsigned short* xr = xT + ((size_t)0 * Bb + arow) * Ee + kg * 8;
    f32x4 a0 = {0.f,0.f,0.f,0.f}, a1 = {0.f,0.f,0.f,0.f};
#pragma unroll 8
    for (int kk = 0; kk < 16; kk++) {
      short8 a = *(const short8*)(xr + kk * 32);
      a0 = __builtin_amdgcn_mfma_f32_16x16x32_bf16(a, W0[kk * 64 + ln], a0, 0, 0, 0);
      a1 = __builtin_amdgcn_mfma_f32_16x16x32_bf16(a, W1[kk * 64 + ln], a1, 0, 0, 0);
    }
    xa0 = a0; xa1 = a1;
  }

// group G readiness: lanes 0..15 each spin on one of the 16 producer flags
#define WAITG(G) do {                                                          \
    if (ln < 16) {                                                             \
      int* fp = flgw + ((G) * 16 + ln) * FPAD;                                 \
      while (__hip_atomic_load(fp, __ATOMIC_RELAXED, __HIP_MEMORY_SCOPE_AGENT) < t) \
        __builtin_amdgcn_s_sleep(1);                                           \
    }                                                                          \
    asm volatile("" ::: "memory");                                             \
  } while (0)

#define LOADG(F, G) do {                                                       \
    F[0] = *(const short8*)(hr + (4 * (G) + 0) * 2048);                        \
    F[1] = *(const short8*)(hr + (4 * (G) + 1) * 2048);                        \
    F[2] = *(const short8*)(hr + (4 * (G) + 2) * 2048);                        \
    F[3] = *(const short8*)(hr + (4 * (G) + 3) * 2048);                        \
  } while (0)

#define MFMAG(F, G) do {                                                       \
    a0 = __builtin_amdgcn_mfma_f32_16x16x32_bf16(F[0], W0[(16 + 4 * (G) + 0) * 64 + ln], a0, 0, 0, 0); \
    a1 = __builtin_amdgcn_mfma_f32_16x16x32_bf16(F[0], W1[(16 + 4 * (G) + 0) * 64 + ln], a1, 0, 0, 0); \
    a0 = __builtin_amdgcn_mfma_f32_16x16x32_bf16(F[1], W0[(16 + 4 * (G) + 1) * 64 + ln], a0, 0, 0, 0); \
    a1 = __builtin_amdgcn_mfma_f32_16x16x32_bf16(F[1], W1[(16 + 4 * (G) + 1) * 64 + ln], a1, 0, 0, 0); \
    a0 = __builtin_amdgcn_mfma_f32_16x16x32_bf16(F[2], W0[(16 + 4 * (G) + 2) * 64 + ln], a0, 0, 0, 0); \
    a1 = __builtin_amdgcn_mfma_f32_16x16x32_bf16(F[2], W1[(16 + 4 * (G) + 2) * 64 + ln], a1, 0, 0, 0); \
    a0 = __builtin_amdgcn_mfma_f32_16x16x32_bf16(F[3], W0[(16 + 4 * (G) + 3) * 64 + ln], a0, 0, 0, 0); \
    a1 = __builtin_amdgcn_mfma_f32_16x16x32_bf16(F[3], W1[(16 + 4 * (G) + 3) * 64 + ln], a1, 0, 0, 0); \
  } while (0)

  for (int t = 0; t < Tt; t++) {
    // consume hseq[t]: 8 groups of 4 k-slices, pipelined one group ahead with
    // A/B fragment buffers (each buffer consumed by MFMA before its reload).
    // Group g's flags (16 producer blocks) confirm LLC arrival; cached 16B
    // loads then fill L2 once per XCD. kk order identical to R4 (bit-exact).
    const unsigned short* hr = hseq + (size_t)t * (NBLK * Bb * HIDB) + kg * 512 + arow * 8;
    f32x4 a0 = xa0, a1 = xa1;
    short8 fA[4], fB[4];
    WAITG(0); LOADG(fA, 0);
    WAITG(1); LOADG(fB, 1); MFMAG(fA, 0);
    WAITG(2); LOADG(fA, 2); MFMAG(fB, 1);
    WAITG(3); LOADG(fB, 3); MFMAG(fA, 2);
    WAITG(4); LOADG(fA, 4); MFMAG(fB, 3);
    WAITG(5); LOADG(fB, 5); MFMAG(fA, 4);
    WAITG(6); LOADG(fA, 6); MFMAG(fB, 5);
    WAITG(7); LOADG(fB, 7); MFMAG(fA, 6);
    MFMAG(fB, 7);

    // cell update: tile0 lane c<8 holds i (c>=8: j), tile1 holds f (o). One
    // shfl_xor(8) gives each lane all 4 gates; lane pair (c, c^8) redundant.
    float hnew[4];
#pragma unroll
    for (int r = 0; r < 4; r++) {
      const float p0 = a0[r], p1 = a1[r];
      const float s0 = __shfl_xor(p0, 8), s1 = __shfl_xor(p1, 8);
      const float gi = (lo ? p0 : s0) + bi;
      const float gj = (lo ? s0 : p0) + bj;
      const float gf = (lo ? p1 : s1) + bff;
      const float go = (lo ? s1 : p1) + bo;
      const float cn = cstate[r] * fsig(gf + 1.0f) + fsig(gi) * ftanhf(gj);
      cstate[r] = cn;
      hnew[r] = ftanhf(cn) * fsig(go);
    }

    if (t < Tt - 1) {
      // pack hid pairs into 4B words; even-lo lanes store agent-coherent
      // (write-through to LLC). Block-major: wave writes private 256B.
      unsigned int hw[4];
#pragma unroll
      for (int r = 0; r < 4; r++) {
        unsigned short us = f2bf(hnew[r]);
        unsigned short ps = (unsigned short)__shfl_xor((int)us, 1);
        hw[r] = (unsigned)us | ((unsigned)ps << 16);
      }
      unsigned int* hob = (unsigned int*)hseq + (size_t)(t + 1) * (NBLK * Bb * HIDB / 2)
                          + bc * (Bb * HIDB / 2);
      if (lo && !(c & 1)) {
#pragma unroll
        for (int r = 0; r < 4; r++)
          __hip_atomic_store(hob + (rbase + r) * 4 + ((c & 7) >> 1),
                             hw[r], __ATOMIC_RELAXED, __HIP_MEMORY_SCOPE_AGENT);
      }
      // wave-local drain: h stores acked at coherence point before flag store
      asm volatile("s_waitcnt vmcnt(0)" ::: "memory");
      if (ln == 0)
        __hip_atomic_store(myslot, t + 1, __ATOMIC_RELAXED, __HIP_MEMORY_SCOPE_AGENT);
      // x-part MFMAs for t+1 (h-independent, L2-cached); consumers of our
      // slice are already pipelining through other groups meanwhile.
      {
        const unsigned short* xr = xT + ((size_t)(t + 1) * Bb + arow) * Ee + kg * 8;
        f32x4 b0 = {0.f,0.f,0.f,0.f}, b1 = {0.f,0.f,0.f,0.f};
#pragma unroll 8
        for (int kk = 0; kk < 16; kk++) {
          short8 a = *(const short8*)(xr + kk * 32);
          b0 = __builtin_amdgcn_mfma_f32_16x16x32_bf16(a, W0[kk * 64 + ln], b0, 0, 0, 0);
          b1 = __builtin_amdgcn_mfma_f32_16x16x32_bf16(a, W1[kk * 64 + ln], b1, 0, 0, 0);
        }
        xa0 = b0; xa1 = b1;
      }
    } else {
      if (lo) {
#pragma unroll
        for (int r = 0; r < 4; r++) h_f32[(rbase + r) * Hh + hid] = hnew[r];
      }
    }
  }
#undef WAITG
#undef LOADG
#undef MFMAG
}

// ---- classifier: pred = h @ outW + outb, softmax, per-row CE --------------
__global__ __launch_bounds__(256) void classifier_kernel(
    const float* __restrict__ h, const float* __restrict__ outW,
    const float* __restrict__ outb, const float* __restrict__ y,
    float* __restrict__ out, float* __restrict__ losses) {
  __shared__ float red[256];
  const int brow = blockIdx.x;
  const int tid = threadIdx.x;
  const int cc = tid & 31;
  const int part = tid >> 5;
  const float* hr = h + brow * Hh;
  float p = 0.f;
  for (int k = part * 128; k < part * 128 + 128; k++)
    p += hr[k] * outW[k * Cc + cc];
  red[tid] = p;
  __syncthreads();
  if (part < 4) red[tid] += red[tid + 128];
  __syncthreads();
  if (part < 2) red[tid] += red[tid + 64];
  __syncthreads();
  if (part < 1) red[tid] += red[tid + 32];
  __syncthreads();
  if (tid < 32) {
    const float logit = red[tid] + outb[tid];
    float m = logit;
    for (int off = 16; off >= 1; off >>= 1) m = fmaxf(m, __shfl_xor(m, off));
    const float e = __expf(logit - m);
    float s = e;
    for (int off = 16; off >= 1; off >>= 1) s += __shfl_xor(s, off);
    out[brow * Cc + tid] = logit;
    out[Bb * Cc + brow * Cc + tid] = e / s;
    const float logp = (logit - m) - __logf(s);
    float contrib = y[brow * Cc + tid] * logp;
    for (int off = 16; off >= 1; off >>= 1) contrib += __shfl_xor(contrib, off);
    if (tid == 0) losses[brow] = -contrib;
  }
}

__global__ __launch_bounds__(64) void finalize_kernel(const float* __restrict__ losses,
                                                      float* __restrict__ out) {
  float v = losses[threadIdx.x];
  for (int off = 32; off >= 1; off >>= 1) v += __shfl_down(v, off);
  if (threadIdx.x == 0) out[2 * Bb * Cc] = v * (1.0f / Bb);
}

extern "C" void kernel_launch(void* const* d_in, const int* in_sizes, int n_in,
                              void* d_out, int out_size, void* d_ws, size_t ws_size,
                              hipStream_t stream) {
  const float* x    = (const float*)d_in[0];
  const float* y    = (const float*)d_in[1];
  // d_in[2] = seqlen (unused)
  const float* W    = (const float*)d_in[3];
  const float* bias = (const float*)d_in[4];
  const float* outW = (const float*)d_in[5];
  const float* outb = (const float*)d_in[6];
  float* out = (float*)d_out;

  char* wsp = (char*)d_ws;
  size_t off = 0;
  auto walloc = [&](size_t bytes) -> void* {
    void* p = wsp + off;
    off += (bytes + 255) & ~(size_t)255;
    return p;
  };
  unsigned short* xT   = (unsigned short*)walloc((size_t)Bb * Tt * Ee * 2);         // 32 MiB
  unsigned short* Wpk  = (unsigned short*)walloc((size_t)NBLK * 2 * NKS * 64 * 16); // 12 MiB
  unsigned short* hseq = (unsigned short*)walloc((size_t)Tt * Bb * Hh * 2);         // 64 MiB rotating h
  float* hf     = (float*)walloc((size_t)Bb * Hh * 4);
  float* losses = (float*)walloc(256);
  int* flg      = (int*)walloc(4 * NBLK * FPAD * 4);                                // 64 KiB flags
  (void)ws_size; (void)in_sizes; (void)n_in; (void)out_size;

  transpose_x_kernel<<<Bb * Tt, 256, 0, stream>>>(x, xT);
  pack_w_kernel<<<NBLK * 2 * NKS, 64, 0, stream>>>(W, Wpk);
  init_state_kernel<<<(Bb * Hh) / 256, 256, 0, stream>>>(hseq, flg);

  lstm_persist<<<NBLK, 256, 0, stream>>>(xT, Wpk, bias, hseq, hf, flg);

  classifier_kernel<<<Bb, 256, 0, stream>>>(hf, outW, outb, y, out, losses);
  finalize_kernel<<<1, 64, 0, stream>>>(losses, out);
}

// Round 7
// 3886.637 us; speedup vs baseline: 2.3200x; 1.0214x over previous
//
#include <hip/hip_runtime.h>
#include <hip/hip_bf16.h>

// SentenceClassifier: LSTM(B=64,T=512,E=512,H=1024) -> h_T @ outW + outb -> softmax/CE
// Persistent-kernel, 128 blocks x 256 thr, block owns 8 hidden units (32 gate
// cols, W slice 96KB LDS). R7: DEEP REGISTER BURST -- R6 profiling showed each
// XCD's h fill comes from HBM (FETCH 1.03MB/step = 8x128KB) and the 1-group-
// deep pipeline exposed ~8 load latencies (~4us of the 7.75us step). Now: one
// wait-all (2 flag slots/lane), then ALL 32 16B h-loads issued back-to-back
// into registers (128 VGPRs payload, fine at 1 block/CU with 512-VGPR budget),
// then 64 MFMAs -- exposes ~1 load latency. kk order unchanged (bit-exact).
// h: rotating cold buffers (64MiB), block-major [bc][row][8hid]; producers
// store agent-scope write-through then vmcnt(0)+flag; consumers plain cached
// loads on cold addresses. No __syncthreads in t-loop. Per-wave flag domains.

#define Bb 64
#define Tt 512
#define Ee 512
#define Hh 1024
#define Cc 32
#define G4 4096
#define NKS 48     // (E+H)/32
#define NBLK 128
#define HIDB 8     // hid units per block
#define FPAD 32    // flag slot pad (ints) = 128B

typedef __attribute__((ext_vector_type(8))) short short8;
typedef __attribute__((ext_vector_type(4))) float f32x4;

__device__ __forceinline__ unsigned short f2bf(float f) {
  __hip_bfloat16 h = __float2bfloat16(f);
  union { __hip_bfloat16 h; unsigned short u; } cv; cv.h = h; return cv.u;
}
static __device__ __forceinline__ float fsig(float x) { return 1.0f / (1.0f + __expf(-x)); }
static __device__ __forceinline__ float ftanhf(float x) {
  float e = __expf(-2.0f * fabsf(x));
  float t = (1.0f - e) / (1.0f + e);
  return copysignf(t, x);
}

// ---- x [B,T,E] f32 -> xT [T,B,E] bf16 (contiguous 64KB window per step) ----
__global__ __launch_bounds__(256) void transpose_x_kernel(const float* __restrict__ x,
                                                          unsigned short* __restrict__ xT) {
  const int bid = blockIdx.x;          // row*Tt + t
  const int row = bid >> 9, t = bid & (Tt - 1);
  const int e = threadIdx.x * 2;
  const float* src = x + ((size_t)row * Tt + t) * Ee + e;
  float2 v = *(const float2*)src;
  ushort2 o; o.x = f2bf(v.x); o.y = f2bf(v.y);
  *(ushort2*)(xT + ((size_t)t * Bb + row) * Ee + e) = o;
}

// ---- W [1536,4096] f32 -> per-block B-frag-packed bf16 --------------------
__global__ __launch_bounds__(64) void pack_w_kernel(const float* __restrict__ W,
                                                    unsigned short* __restrict__ Wpk) {
  const int fid = blockIdx.x;          // blk*96 + tau*48 + ks
  const int l = threadIdx.x;
  const int blk = fid / 96, rem = fid % 96;
  const int tau = rem / 48, ks = rem % 48;
  const int c = l & 15;
  const int col = (2 * tau + (c >> 3)) * Hh + blk * HIDB + (c & 7);
  const int k0 = ks * 32 + (l >> 4) * 8;
  short8 v;
#pragma unroll
  for (int i = 0; i < 8; i++) v[i] = (short)f2bf(W[(size_t)(k0 + i) * G4 + col]);
  *(short8*)(Wpk + ((size_t)fid * 64 + l) * 8) = v;
}

// ---- zero h buffer 0 + flag state -----------------------------------------
__global__ __launch_bounds__(256) void init_state_kernel(unsigned short* __restrict__ h0,
                                                         int* __restrict__ flg) {
  int i = blockIdx.x * 256 + threadIdx.x;   // grid covers Bb*Hh
  h0[i] = 0;
  if (i < 4 * NBLK * FPAD) flg[i] = 0;      // 512 padded flag slots
}

// ---- persistent LSTM kernel ----------------------------------------------
__global__ __launch_bounds__(256, 1) void lstm_persist(
    const unsigned short* __restrict__ xT, const unsigned short* __restrict__ Wpk,
    const float* __restrict__ bias,
    unsigned short* __restrict__ hseq,   // Tt buffers, block-major [bc][row][8hid]
    float* __restrict__ h_f32, int* __restrict__ flg) {
  __shared__ short8 Wl[2 * NKS * 64];       // 96 KiB
  const int bc = blockIdx.x;
  const int tid = threadIdx.x;

  { // one-time: W slice -> LDS (linear 96KB copy)
    const short8* src = (const short8*)Wpk + (size_t)bc * (2 * NKS * 64);
    for (int i = tid; i < 2 * NKS * 64; i += 256) Wl[i] = src[i];
  }

  const int wv = tid >> 6, ln = tid & 63;
  const int c = ln & 15, kg = ln >> 4;
  const int arow = wv * 16 + c;        // A-frag row = batch index
  const int rbase = wv * 16 + kg * 4;  // D rows (m89 layout: row=(l>>4)*4+r, col=l&15)
  const int hid = bc * HIDB + (c & 7);
  const bool lo = (c < 8);
  const float bi = bias[hid], bj = bias[Hh + hid];
  const float bff = bias[2 * Hh + hid], bo = bias[3 * Hh + hid];
  float cstate[4] = {0.f, 0.f, 0.f, 0.f};

  __syncthreads();                      // W in LDS ready (only barrier in kernel)

  const short8* W0 = Wl;                // tile0 (gates i,j)
  const short8* W1 = Wl + NKS * 64;     // tile1 (gates f,o)

  int* flgw = flg + wv * NBLK * FPAD;   // own wave's flag domain
  int* myslot = flgw + bc * FPAD;
  int* slot0 = flgw + ln * FPAD;        // wait-all: 2 slots per lane
  int* slot1 = flgw + (ln + 64) * FPAD;

  f32x4 xa0, xa1;
  // x-part for t=0
  {
    const unsigned short* xr = xT + ((size_t)0 * Bb + arow) * Ee + kg * 8;
    f32x4 a0 = {0.f,0.f,0.f,0.f}, a1 = {0.f,0.f,0.f,0.f};
#pragma unroll 8
    for (int kk = 0; kk < 16; kk++) {
      short8 a = *(const short8*)(xr + kk * 32);
      a0 = __builtin_amdgcn_mfma_f32_16x16x32_bf16(a, W0[kk * 64 + ln], a0, 0, 0, 0);
      a1 = __builtin_amdgcn_mfma_f32_16x16x32_bf16(a, W1[kk * 64 + ln], a1, 0, 0, 0);
    }
    xa0 = a0; xa1 = a1;
  }

  for (int t = 0; t < Tt; t++) {
    // ---- wait-all: producers (own wave-plane, all 128 blocks) flagged step t.
    // Producers are symmetric so all flags land ~together (R6 showed per-group
    // waits buy nothing over wait-all at detection time).
    for (;;) {
      int v0 = __hip_atomic_load(slot0, __ATOMIC_RELAXED, __HIP_MEMORY_SCOPE_AGENT);
      int v1 = __hip_atomic_load(slot1, __ATOMIC_RELAXED, __HIP_MEMORY_SCOPE_AGENT);
      if (v0 >= t && v1 >= t) break;
      __builtin_amdgcn_s_sleep(1);
    }
    asm volatile("" ::: "memory");      // no hoist of h loads above the wait

    // ---- deep burst: all 32 independent 16B h-loads issued back-to-back
    // (128 payload VGPRs; 32 outstanding vmem ops -> ~1 exposed latency).
    const unsigned short* hr = hseq + (size_t)t * (NBLK * Bb * HIDB) + kg * 512 + arow * 8;
    short8 f[32];
#pragma unroll
    for (int kk = 0; kk < 32; kk++) f[kk] = *(const short8*)(hr + kk * 2048);

    f32x4 a0 = xa0, a1 = xa1;
#pragma unroll
    for (int kk = 0; kk < 32; kk++) {
      a0 = __builtin_amdgcn_mfma_f32_16x16x32_bf16(f[kk], W0[(16 + kk) * 64 + ln], a0, 0, 0, 0);
      a1 = __builtin_amdgcn_mfma_f32_16x16x32_bf16(f[kk], W1[(16 + kk) * 64 + ln], a1, 0, 0, 0);
    }

    // cell update: tile0 lane c<8 holds i (c>=8: j), tile1 holds f (o). One
    // shfl_xor(8) gives each lane all 4 gates; lane pair (c, c^8) redundant.
    float hnew[4];
#pragma unroll
    for (int r = 0; r < 4; r++) {
      const float p0 = a0[r], p1 = a1[r];
      const float s0 = __shfl_xor(p0, 8), s1 = __shfl_xor(p1, 8);
      const float gi = (lo ? p0 : s0) + bi;
      const float gj = (lo ? s0 : p0) + bj;
      const float gf = (lo ? p1 : s1) + bff;
      const float go = (lo ? s1 : p1) + bo;
      const float cn = cstate[r] * fsig(gf + 1.0f) + fsig(gi) * ftanhf(gj);
      cstate[r] = cn;
      hnew[r] = ftanhf(cn) * fsig(go);
    }

    if (t < Tt - 1) {
      // pack hid pairs into 4B words; even-lo lanes store agent-coherent
      // (write-through, visible at coherence point). Block-major: wave-private 256B.
      unsigned int hw[4];
#pragma unroll
      for (int r = 0; r < 4; r++) {
        unsigned short us = f2bf(hnew[r]);
        unsigned short ps = (unsigned short)__shfl_xor((int)us, 1);
        hw[r] = (unsigned)us | ((unsigned)ps << 16);
      }
      unsigned int* hob = (unsigned int*)hseq + (size_t)(t + 1) * (NBLK * Bb * HIDB / 2)
                          + bc * (Bb * HIDB / 2);
      if (lo && !(c & 1)) {
#pragma unroll
        for (int r = 0; r < 4; r++)
          __hip_atomic_store(hob + (rbase + r) * 4 + ((c & 7) >> 1),
                             hw[r], __ATOMIC_RELAXED, __HIP_MEMORY_SCOPE_AGENT);
      }
      // wave-local drain: h stores acked at coherence point before flag store
      asm volatile("s_waitcnt vmcnt(0)" ::: "memory");
      if (ln == 0)
        __hip_atomic_store(myslot, t + 1, __ATOMIC_RELAXED, __HIP_MEMORY_SCOPE_AGENT);
      // x-part MFMAs for t+1 (h-independent, L2-cached) while flags propagate
      {
        const unsigned short* xr = xT + ((size_t)(t + 1) * Bb + arow) * Ee + kg * 8;
        f32x4 b0 = {0.f,0.f,0.f,0.f}, b1 = {0.f,0.f,0.f,0.f};
#pragma unroll 8
        for (int kk = 0; kk < 16; kk++) {
          short8 a = *(const short8*)(xr + kk * 32);
          b0 = __builtin_amdgcn_mfma_f32_16x16x32_bf16(a, W0[kk * 64 + ln], b0, 0, 0, 0);
          b1 = __builtin_amdgcn_mfma_f32_16x16x32_bf16(a, W1[kk * 64 + ln], b1, 0, 0, 0);
        }
        xa0 = b0; xa1 = b1;
      }
    } else {
      if (lo) {
#pragma unroll
        for (int r = 0; r < 4; r++) h_f32[(rbase + r) * Hh + hid] = hnew[r];
      }
    }
  }
}

// ---- classifier: pred = h @ outW + outb, softmax, per-row CE --------------
__global__ __launch_bounds__(256) void classifier_kernel(
    const float* __restrict__ h, const float* __restrict__ outW,
    const float* __restrict__ outb, const float* __restrict__ y,
    float* __restrict__ out, float* __restrict__ losses) {
  __shared__ float red[256];
  const int brow = blockIdx.x;
  const int tid = threadIdx.x;
  const int cc = tid & 31;
  const int part = tid >> 5;
  const float* hr = h + brow * Hh;
  float p = 0.f;
  for (int k = part * 128; k < part * 128 + 128; k++)
    p += hr[k] * outW[k * Cc + cc];
  red[tid] = p;
  __syncthreads();
  if (part < 4) red[tid] += red[tid + 128];
  __syncthreads();
  if (part < 2) red[tid] += red[tid + 64];
  __syncthreads();
  if (part < 1) red[tid] += red[tid + 32];
  __syncthreads();
  if (tid < 32) {
    const float logit = red[tid] + outb[tid];
    float m = logit;
    for (int off = 16; off >= 1; off >>= 1) m = fmaxf(m, __shfl_xor(m, off));
    const float e = __expf(logit - m);
    float s = e;
    for (int off = 16; off >= 1; off >>= 1) s += __shfl_xor(s, off);
    out[brow * Cc + tid] = logit;
    out[Bb * Cc + brow * Cc + tid] = e / s;
    const float logp = (logit - m) - __logf(s);
    float contrib = y[brow * Cc + tid] * logp;
    for (int off = 16; off >= 1; off >>= 1) contrib += __shfl_xor(contrib, off);
    if (tid == 0) losses[brow] = -contrib;
  }
}

__global__ __launch_bounds__(64) void finalize_kernel(const float* __restrict__ losses,
                                                      float* __restrict__ out) {
  float v = losses[threadIdx.x];
  for (int off = 32; off >= 1; off >>= 1) v += __shfl_down(v, off);
  if (threadIdx.x == 0) out[2 * Bb * Cc] = v * (1.0f / Bb);
}

extern "C" void kernel_launch(void* const* d_in, const int* in_sizes, int n_in,
                              void* d_out, int out_size, void* d_ws, size_t ws_size,
                              hipStream_t stream) {
  const float* x    = (const float*)d_in[0];
  const float* y    = (const float*)d_in[1];
  // d_in[2] = seqlen (unused)
  const float* W    = (const float*)d_in[3];
  const float* bias = (const float*)d_in[4];
  const float* outW = (const float*)d_in[5];
  const float* outb = (const float*)d_in[6];
  float* out = (float*)d_out;

  char* wsp = (char*)d_ws;
  size_t off = 0;
  auto walloc = [&](size_t bytes) -> void* {
    void* p = wsp + off;
    off += (bytes + 255) & ~(size_t)255;
    return p;
  };
  unsigned short* xT   = (unsigned short*)walloc((size_t)Bb * Tt * Ee * 2);         // 32 MiB
  unsigned short* Wpk  = (unsigned short*)walloc((size_t)NBLK * 2 * NKS * 64 * 16); // 12 MiB
  unsigned short* hseq = (unsigned short*)walloc((size_t)Tt * Bb * Hh * 2);         // 64 MiB rotating h
  float* hf     = (float*)walloc((size_t)Bb * Hh * 4);
  float* losses = (float*)walloc(256);
  int* flg      = (int*)walloc(4 * NBLK * FPAD * 4);                                // 64 KiB flags
  (void)ws_size; (void)in_sizes; (void)n_in; (void)out_size;

  transpose_x_kernel<<<Bb * Tt, 256, 0, stream>>>(x, xT);
  pack_w_kernel<<<NBLK * 2 * NKS, 64, 0, stream>>>(W, Wpk);
  init_state_kernel<<<(Bb * Hh) / 256, 256, 0, stream>>>(hseq, flg);

  lstm_persist<<<NBLK, 256, 0, stream>>>(xT, Wpk, bias, hseq, hf, flg);

  classifier_kernel<<<Bb, 256, 0, stream>>>(hf, outW, outb, y, out, losses);
  finalize_kernel<<<1, 64, 0, stream>>>(losses, out);
}

// Round 8
// 3583.023 us; speedup vs baseline: 2.5166x; 1.0847x over previous
//
#include <hip/hip_runtime.h>
#include <hip/hip_bf16.h>

// SentenceClassifier: LSTM(B=64,T=512,E=512,H=1024) -> h_T @ outW + outb -> softmax/CE
// Persistent-kernel, 128 blocks x 256 thr, block owns 8 hidden units (32 gate
// cols, W slice 96KB LDS). R8: (a) FORCED deep h-load burst -- R7's burst was
// silently re-interleaved by the compiler (VGPR stayed 132); now pinned with
// s_waitcnt vmcnt(0) + "memory" clobber + sched_barrier(0) after the 32-load
// loop, forcing all loads issued before any MFMA (1 exposed latency, ~128
// payload VGPRs). (b) x-part W fragments (same LDS addresses every step)
// hoisted into 128 resident VGPRs -- removes 32 of 96 ds_read_b128/wave/step
// from the CU LDS port. h: rotating cold buffers, block-major [bc][row][8hid];
// producers agent-scope write-through + vmcnt(0) + flag; consumers plain
// cached loads on cold addresses after wait-all. No __syncthreads in t-loop.

#define Bb 64
#define Tt 512
#define Ee 512
#define Hh 1024
#define Cc 32
#define G4 4096
#define NKS 48     // (E+H)/32
#define NBLK 128
#define HIDB 8     // hid units per block
#define FPAD 32    // flag slot pad (ints) = 128B

typedef __attribute__((ext_vector_type(8))) short short8;
typedef __attribute__((ext_vector_type(4))) float f32x4;

__device__ __forceinline__ unsigned short f2bf(float f) {
  __hip_bfloat16 h = __float2bfloat16(f);
  union { __hip_bfloat16 h; unsigned short u; } cv; cv.h = h; return cv.u;
}
static __device__ __forceinline__ float fsig(float x) { return 1.0f / (1.0f + __expf(-x)); }
static __device__ __forceinline__ float ftanhf(float x) {
  float e = __expf(-2.0f * fabsf(x));
  float t = (1.0f - e) / (1.0f + e);
  return copysignf(t, x);
}

// ---- x [B,T,E] f32 -> xT [T,B,E] bf16 (contiguous 64KB window per step) ----
__global__ __launch_bounds__(256) void transpose_x_kernel(const float* __restrict__ x,
                                                          unsigned short* __restrict__ xT) {
  const int bid = blockIdx.x;          // row*Tt + t
  const int row = bid >> 9, t = bid & (Tt - 1);
  const int e = threadIdx.x * 2;
  const float* src = x + ((size_t)row * Tt + t) * Ee + e;
  float2 v = *(const float2*)src;
  ushort2 o; o.x = f2bf(v.x); o.y = f2bf(v.y);
  *(ushort2*)(xT + ((size_t)t * Bb + row) * Ee + e) = o;
}

// ---- W [1536,4096] f32 -> per-block B-frag-packed bf16 --------------------
__global__ __launch_bounds__(64) void pack_w_kernel(const float* __restrict__ W,
                                                    unsigned short* __restrict__ Wpk) {
  const int fid = blockIdx.x;          // blk*96 + tau*48 + ks
  const int l = threadIdx.x;
  const int blk = fid / 96, rem = fid % 96;
  const int tau = rem / 48, ks = rem % 48;
  const int c = l & 15;
  const int col = (2 * tau + (c >> 3)) * Hh + blk * HIDB + (c & 7);
  const int k0 = ks * 32 + (l >> 4) * 8;
  short8 v;
#pragma unroll
  for (int i = 0; i < 8; i++) v[i] = (short)f2bf(W[(size_t)(k0 + i) * G4 + col]);
  *(short8*)(Wpk + ((size_t)fid * 64 + l) * 8) = v;
}

// ---- zero h buffer 0 + flag state -----------------------------------------
__global__ __launch_bounds__(256) void init_state_kernel(unsigned short* __restrict__ h0,
                                                         int* __restrict__ flg) {
  int i = blockIdx.x * 256 + threadIdx.x;   // grid covers Bb*Hh
  h0[i] = 0;
  if (i < 4 * NBLK * FPAD) flg[i] = 0;      // 512 padded flag slots
}

// ---- persistent LSTM kernel ----------------------------------------------
__global__ __launch_bounds__(256, 1) void lstm_persist(
    const unsigned short* __restrict__ xT, const unsigned short* __restrict__ Wpk,
    const float* __restrict__ bias,
    unsigned short* __restrict__ hseq,   // Tt buffers, block-major [bc][row][8hid]
    float* __restrict__ h_f32, int* __restrict__ flg) {
  __shared__ short8 Wl[2 * NKS * 64];       // 96 KiB
  const int bc = blockIdx.x;
  const int tid = threadIdx.x;

  { // one-time: W slice -> LDS (linear 96KB copy)
    const short8* src = (const short8*)Wpk + (size_t)bc * (2 * NKS * 64);
    for (int i = tid; i < 2 * NKS * 64; i += 256) Wl[i] = src[i];
  }

  const int wv = tid >> 6, ln = tid & 63;
  const int c = ln & 15, kg = ln >> 4;
  const int arow = wv * 16 + c;        // A-frag row = batch index
  const int rbase = wv * 16 + kg * 4;  // D rows (m89 layout: row=(l>>4)*4+r, col=l&15)
  const int hid = bc * HIDB + (c & 7);
  const bool lo = (c < 8);
  const float bi = bias[hid], bj = bias[Hh + hid];
  const float bff = bias[2 * Hh + hid], bo = bias[3 * Hh + hid];
  float cstate[4] = {0.f, 0.f, 0.f, 0.f};

  __syncthreads();                      // W in LDS ready (only barrier in kernel)

  const short8* W0 = Wl;                // tile0 (gates i,j)
  const short8* W1 = Wl + NKS * 64;     // tile1 (gates f,o)

  // x-part W fragments: same LDS addresses every step -> hoist to registers
  // (32 short8 = 128 resident VGPRs; removes 32 ds_read_b128/wave/step).
  short8 wx0[16], wx1[16];
#pragma unroll
  for (int kk = 0; kk < 16; kk++) { wx0[kk] = W0[kk * 64 + ln]; wx1[kk] = W1[kk * 64 + ln]; }

  int* flgw = flg + wv * NBLK * FPAD;   // own wave's flag domain
  int* myslot = flgw + bc * FPAD;
  int* slot0 = flgw + ln * FPAD;        // wait-all: 2 slots per lane
  int* slot1 = flgw + (ln + 64) * FPAD;

  f32x4 xa0, xa1;
  // x-part for t=0
  {
    const unsigned short* xr = xT + ((size_t)0 * Bb + arow) * Ee + kg * 8;
    f32x4 a0 = {0.f,0.f,0.f,0.f}, a1 = {0.f,0.f,0.f,0.f};
#pragma unroll
    for (int kk = 0; kk < 16; kk++) {
      short8 a = *(const short8*)(xr + kk * 32);
      a0 = __builtin_amdgcn_mfma_f32_16x16x32_bf16(a, wx0[kk], a0, 0, 0, 0);
      a1 = __builtin_amdgcn_mfma_f32_16x16x32_bf16(a, wx1[kk], a1, 0, 0, 0);
    }
    xa0 = a0; xa1 = a1;
  }

  for (int t = 0; t < Tt; t++) {
    // ---- wait-all: producers (own wave-plane, all 128 blocks) flagged step t.
    for (;;) {
      int v0 = __hip_atomic_load(slot0, __ATOMIC_RELAXED, __HIP_MEMORY_SCOPE_AGENT);
      int v1 = __hip_atomic_load(slot1, __ATOMIC_RELAXED, __HIP_MEMORY_SCOPE_AGENT);
      if (v0 >= t && v1 >= t) break;
      __builtin_amdgcn_s_sleep(1);
    }
    asm volatile("" ::: "memory");      // no hoist of h loads above the wait

    // ---- FORCED deep burst: all 32 independent 16B h-loads issued, then one
    // drain. memory clobber pins the loads above the waitcnt; sched_barrier
    // (rule #18) pins the MFMAs below it. ~128 payload VGPRs live here.
    const unsigned short* hr = hseq + (size_t)t * (NBLK * Bb * HIDB) + kg * 512 + arow * 8;
    short8 f[32];
#pragma unroll
    for (int kk = 0; kk < 32; kk++) f[kk] = *(const short8*)(hr + kk * 2048);
    asm volatile("s_waitcnt vmcnt(0)" ::: "memory");
    __builtin_amdgcn_sched_barrier(0);

    f32x4 a0 = xa0, a1 = xa1;
#pragma unroll
    for (int kk = 0; kk < 32; kk++) {
      a0 = __builtin_amdgcn_mfma_f32_16x16x32_bf16(f[kk], W0[(16 + kk) * 64 + ln], a0, 0, 0, 0);
      a1 = __builtin_amdgcn_mfma_f32_16x16x32_bf16(f[kk], W1[(16 + kk) * 64 + ln], a1, 0, 0, 0);
    }

    // cell update: tile0 lane c<8 holds i (c>=8: j), tile1 holds f (o). One
    // shfl_xor(8) gives each lane all 4 gates; lane pair (c, c^8) redundant.
    float hnew[4];
#pragma unroll
    for (int r = 0; r < 4; r++) {
      const float p0 = a0[r], p1 = a1[r];
      const float s0 = __shfl_xor(p0, 8), s1 = __shfl_xor(p1, 8);
      const float gi = (lo ? p0 : s0) + bi;
      const float gj = (lo ? s0 : p0) + bj;
      const float gf = (lo ? p1 : s1) + bff;
      const float go = (lo ? s1 : p1) + bo;
      const float cn = cstate[r] * fsig(gf + 1.0f) + fsig(gi) * ftanhf(gj);
      cstate[r] = cn;
      hnew[r] = ftanhf(cn) * fsig(go);
    }

    if (t < Tt - 1) {
      // pack hid pairs into 4B words; even-lo lanes store agent-coherent
      // (write-through, visible at coherence point). Block-major: wave-private 256B.
      unsigned int hw[4];
#pragma unroll
      for (int r = 0; r < 4; r++) {
        unsigned short us = f2bf(hnew[r]);
        unsigned short ps = (unsigned short)__shfl_xor((int)us, 1);
        hw[r] = (unsigned)us | ((unsigned)ps << 16);
      }
      unsigned int* hob = (unsigned int*)hseq + (size_t)(t + 1) * (NBLK * Bb * HIDB / 2)
                          + bc * (Bb * HIDB / 2);
      if (lo && !(c & 1)) {
#pragma unroll
        for (int r = 0; r < 4; r++)
          __hip_atomic_store(hob + (rbase + r) * 4 + ((c & 7) >> 1),
                             hw[r], __ATOMIC_RELAXED, __HIP_MEMORY_SCOPE_AGENT);
      }
      // wave-local drain: h stores acked at coherence point before flag store
      asm volatile("s_waitcnt vmcnt(0)" ::: "memory");
      if (ln == 0)
        __hip_atomic_store(myslot, t + 1, __ATOMIC_RELAXED, __HIP_MEMORY_SCOPE_AGENT);
      // x-part MFMAs for t+1 (h-independent, W from registers) while flags fly
      {
        const unsigned short* xr = xT + ((size_t)(t + 1) * Bb + arow) * Ee + kg * 8;
        f32x4 b0 = {0.f,0.f,0.f,0.f}, b1 = {0.f,0.f,0.f,0.f};
#pragma unroll
        for (int kk = 0; kk < 16; kk++) {
          short8 a = *(const short8*)(xr + kk * 32);
          b0 = __builtin_amdgcn_mfma_f32_16x16x32_bf16(a, wx0[kk], b0, 0, 0, 0);
          b1 = __builtin_amdgcn_mfma_f32_16x16x32_bf16(a, wx1[kk], b1, 0, 0, 0);
        }
        xa0 = b0; xa1 = b1;
      }
    } else {
      if (lo) {
#pragma unroll
        for (int r = 0; r < 4; r++) h_f32[(rbase + r) * Hh + hid] = hnew[r];
      }
    }
  }
}

// ---- classifier: pred = h @ outW + outb, softmax, per-row CE --------------
__global__ __launch_bounds__(256) void classifier_kernel(
    const float* __restrict__ h, const float* __restrict__ outW,
    const float* __restrict__ outb, const float* __restrict__ y,
    float* __restrict__ out, float* __restrict__ losses) {
  __shared__ float red[256];
  const int brow = blockIdx.x;
  const int tid = threadIdx.x;
  const int cc = tid & 31;
  const int part = tid >> 5;
  const float* hr = h + brow * Hh;
  float p = 0.f;
  for (int k = part * 128; k < part * 128 + 128; k++)
    p += hr[k] * outW[k * Cc + cc];
  red[tid] = p;
  __syncthreads();
  if (part < 4) red[tid] += red[tid + 128];
  __syncthreads();
  if (part < 2) red[tid] += red[tid + 64];
  __syncthreads();
  if (part < 1) red[tid] += red[tid + 32];
  __syncthreads();
  if (tid < 32) {
    const float logit = red[tid] + outb[tid];
    float m = logit;
    for (int off = 16; off >= 1; off >>= 1) m = fmaxf(m, __shfl_xor(m, off));
    const float e = __expf(logit - m);
    float s = e;
    for (int off = 16; off >= 1; off >>= 1) s += __shfl_xor(s, off);
    out[brow * Cc + tid] = logit;
    out[Bb * Cc + brow * Cc + tid] = e / s;
    const float logp = (logit - m) - __logf(s);
    float contrib = y[brow * Cc + tid] * logp;
    for (int off = 16; off >= 1; off >>= 1) contrib += __shfl_xor(contrib, off);
    if (tid == 0) losses[brow] = -contrib;
  }
}

__global__ __launch_bounds__(64) void finalize_kernel(const float* __restrict__ losses,
                                                      float* __restrict__ out) {
  float v = losses[threadIdx.x];
  for (int off = 32; off >= 1; off >>= 1) v += __shfl_down(v, off);
  if (threadIdx.x == 0) out[2 * Bb * Cc] = v * (1.0f / Bb);
}

extern "C" void kernel_launch(void* const* d_in, const int* in_sizes, int n_in,
                              void* d_out, int out_size, void* d_ws, size_t ws_size,
                              hipStream_t stream) {
  const float* x    = (const float*)d_in[0];
  const float* y    = (const float*)d_in[1];
  // d_in[2] = seqlen (unused)
  const float* W    = (const float*)d_in[3];
  const float* bias = (const float*)d_in[4];
  const float* outW = (const float*)d_in[5];
  const float* outb = (const float*)d_in[6];
  float* out = (float*)d_out;

  char* wsp = (char*)d_ws;
  size_t off = 0;
  auto walloc = [&](size_t bytes) -> void* {
    void* p = wsp + off;
    off += (bytes + 255) & ~(size_t)255;
    return p;
  };
  unsigned short* xT   = (unsigned short*)walloc((size_t)Bb * Tt * Ee * 2);         // 32 MiB
  unsigned short* Wpk  = (unsigned short*)walloc((size_t)NBLK * 2 * NKS * 64 * 16); // 12 MiB
  unsigned short* hseq = (unsigned short*)walloc((size_t)Tt * Bb * Hh * 2);         // 64 MiB rotating h
  float* hf     = (float*)walloc((size_t)Bb * Hh * 4);
  float* losses = (float*)walloc(256);
  int* flg      = (int*)walloc(4 * NBLK * FPAD * 4);                                // 64 KiB flags
  (void)ws_size; (void)in_sizes; (void)n_in; (void)out_size;

  transpose_x_kernel<<<Bb * Tt, 256, 0, stream>>>(x, xT);
  pack_w_kernel<<<NBLK * 2 * NKS, 64, 0, stream>>>(W, Wpk);
  init_state_kernel<<<(Bb * Hh) / 256, 256, 0, stream>>>(hseq, flg);

  lstm_persist<<<NBLK, 256, 0, stream>>>(xT, Wpk, bias, hseq, hf, flg);

  classifier_kernel<<<Bb, 256, 0, stream>>>(hf, outW, outb, y, out, losses);
  finalize_kernel<<<1, 64, 0, stream>>>(losses, out);
}